// Round 15
// baseline (224.040 us; speedup 1.0000x reference)
//
#include <hip/hip_runtime.h>
#include <hip/hip_bf16.h>
#include <stdint.h>

typedef unsigned short u16;
typedef __attribute__((ext_vector_type(8))) short bf16x8;
typedef __attribute__((ext_vector_type(4))) short bf16x4;
typedef __attribute__((ext_vector_type(4))) float f32x4;
typedef __attribute__((ext_vector_type(4))) unsigned short u16x4;

__device__ __forceinline__ float bf2f(u16 u) {
  union { unsigned i; float f; } c; c.i = ((unsigned)u) << 16; return c.f;
}
__device__ __forceinline__ u16 f2bf(float f) {
  union { float f; unsigned i; } c; c.f = f;
  unsigned r = c.i + 0x7FFFu + ((c.i >> 16) & 1u);
  return (u16)(r >> 16);
}
__device__ __forceinline__ unsigned cvt_pk(float lo, float hi) {
  unsigned r;
  asm("v_cvt_pk_bf16_f32 %0, %1, %2" : "=v"(r) : "v"(lo), "v"(hi));
  return r;
}
__device__ __forceinline__ void gl2lds16(const u16* g, u16* l) {
  __builtin_amdgcn_global_load_lds(
      (const __attribute__((address_space(1))) unsigned int*)(uintptr_t)g,
      (__attribute__((address_space(3))) unsigned int*)(uintptr_t)l,
      16, 0, 0);
}

// ---------------- K0: convert weights to bf16 ----------------
__global__ void k_prep(const float* __restrict__ wo, const float* __restrict__ wq,
                       const float* __restrict__ wk, const float* __restrict__ wv,
                       u16* __restrict__ WT, u16* __restrict__ WQKV) {
  int i = blockIdx.x * 256 + threadIdx.x;
  if (i < 9 * 128 * 128) {
    int c = i & 127;
    int o = (i >> 7) & 127;
    int tap = i >> 14;
    WT[i] = f2bf(wo[((o * 128 + c) * 3 + tap / 3) * 3 + tap % 3]);
  } else {
    int j = i - 9 * 128 * 128;
    if (j < 3 * 16384) {
      int sel = j >> 14, rest = j & 16383;
      const float* w = sel == 0 ? wq : (sel == 1 ? wk : wv);
      WQKV[j] = f2bf(w[rest]);
    }
  }
}

// ---------------- K1: QKV 1x1 conv + window scatter, sel in grid.y ----------------
// grid (1024, 3): x: blk = b*512 + tw*32 + th; y = sel. block 256.
// Q/K/V layout: [bh][s][d], d = pixw*32 + dph. Xt chunk-XOR swizzled; Ot aliases Xt.
__global__ __launch_bounds__(256) void k_qkv(
    const float* __restrict__ x, const u16* __restrict__ WQKV,
    const float* __restrict__ bq, const float* __restrict__ bk,
    const float* __restrict__ bv,
    u16* __restrict__ Q, u16* __restrict__ K, u16* __restrict__ V) {
  const int sel = blockIdx.y;
  const int blk = blockIdx.x;
  const int b = blk >> 9;
  const int t = blk & 511;
  const int th = t & 31, tw = t >> 5;
  const int h0 = th * 8, w0 = tw * 16;
  const int s0 = th * 32 + tw * 2;
  const int tid = threadIdx.x, lane = tid & 63, wid = tid >> 6;
  const int wr = wid >> 1, wc = wid & 1;
  const int g = lane >> 4, l15 = lane & 15;

  __shared__ u16 Xt[128 * 136];   // [p][chunk16 swz + pad]; Ot aliases after MFMA
  u16* Ot = Xt;

  #pragma unroll
  for (int j = 0; j < 4; ++j) {
    int lin = j * 256 + tid;            // 0..1023
    int c2 = lin >> 4;                  // 0..63
    int ci = lin & 15;
    int c = c2 * 2;
    int lh = ci >> 1, lw8 = (ci & 1) * 8;
    const float* s0p = x + (size_t)b * 8388608 + (size_t)c * 65536 + (h0 + lh) * 256 + w0 + lw8;
    const float* s1p = s0p + 65536;     // channel c+1
    float4 a0 = *(const float4*)s0p;
    float4 a1 = *(const float4*)(s0p + 4);
    float4 c0 = *(const float4*)s1p;
    float4 c1 = *(const float4*)(s1p + 4);
    int px = ci * 8;                    // 8 consecutive pixels, same lh
    int ch = c >> 3;
    int chp = (ch & 8) | ((ch & 7) ^ (ci & 7));
    unsigned* dst = (unsigned*)&Xt[px * 136 + chp * 8 + (c & 7)];
    dst[0 * 68] = cvt_pk(a0.x, c0.x);
    dst[1 * 68] = cvt_pk(a0.y, c0.y);
    dst[2 * 68] = cvt_pk(a0.z, c0.z);
    dst[3 * 68] = cvt_pk(a0.w, c0.w);
    dst[4 * 68] = cvt_pk(a1.x, c1.x);
    dst[5 * 68] = cvt_pk(a1.y, c1.y);
    dst[6 * 68] = cvt_pk(a1.z, c1.z);
    dst[7 * 68] = cvt_pk(a1.w, c1.w);
  }
  __syncthreads();

  const u16* w = WQKV + sel * 16384;
  const float* bias = sel == 0 ? bq : (sel == 1 ? bk : bv);
  u16* qkv = sel == 0 ? Q : (sel == 1 ? K : V);

  f32x4 acc[4][4] = {};
  #pragma unroll
  for (int k0 = 0; k0 < 128; k0 += 32) {
    bf16x8 a[4], bb[4];
    #pragma unroll
    for (int m = 0; m < 4; ++m) {
      int o = wr * 64 + m * 16 + l15;
      a[m] = *(const bf16x8*)(w + o * 128 + k0 + g * 8);
    }
    #pragma unroll
    for (int n = 0; n < 4; ++n) {
      int p = wc * 64 + n * 16 + l15;
      int ch = (k0 >> 3) + g;
      int chp = (ch & 8) | ((ch & 7) ^ ((p >> 3) & 7));
      bb[n] = *(const bf16x8*)&Xt[p * 136 + chp * 8];
    }
    #pragma unroll
    for (int m = 0; m < 4; ++m)
      #pragma unroll
      for (int n = 0; n < 4; ++n)
        acc[m][n] = __builtin_amdgcn_mfma_f32_16x16x32_bf16(a[m], bb[n], acc[m][n], 0, 0, 0);
  }

  float4 bias4[4];
  #pragma unroll
  for (int m = 0; m < 4; ++m)
    bias4[m] = *(const float4*)&bias[wr * 64 + m * 16 + g * 4];

  __syncthreads();                      // all Xt reads done; Ot may overwrite
  #pragma unroll
  for (int m = 0; m < 4; ++m) {
    int o0 = wr * 64 + m * 16 + g * 4;
    #pragma unroll
    for (int n = 0; n < 4; ++n) {
      int p = wc * 64 + n * 16 + l15;   // full 0..127
      unsigned r0 = cvt_pk(acc[m][n][0] + bias4[m].x, acc[m][n][1] + bias4[m].y);
      unsigned r1 = cvt_pk(acc[m][n][2] + bias4[m].z, acc[m][n][3] + bias4[m].w);
      unsigned* dp = (unsigned*)&Ot[p * 136 + o0];
      dp[0] = r0; dp[1] = r1;
    }
  }
  __syncthreads();
  // stores: it = head*2+s2; 256 threads cover 64 pixw x 4 dphc = 4KB contiguous
  #pragma unroll
  for (int it = 0; it < 8; ++it) {
    int head = it >> 1, s2 = it & 1;
    int pixw = tid >> 2;                // 0..63
    int dphc = tid & 3;
    int pl = (pixw >> 3) * 16 + s2 * 8 + (pixw & 7);
    bf16x8 vv = *(const bf16x8*)&Ot[pl * 136 + head * 32 + dphc * 8];
    size_t gaddr = ((size_t)((b * 4 + head) * 1024 + s0 + s2)) * 2048 + pixw * 32 + dphc * 8;
    *(bf16x8*)(qkv + gaddr) = vv;
  }
}

// ---------------- K2: ATT = Q K^T * scale ----------------
// grid 512 1-D: bh = wgid&7 (one bh per XCD); tm = tile&7 fastest.
__global__ __launch_bounds__(256) void k_qk(const u16* __restrict__ Q,
                                            const u16* __restrict__ K,
                                            float* __restrict__ ATT) {
  const int bh = blockIdx.x & 7;
  const int tile = blockIdx.x >> 3;
  const int tm = tile & 7, tn = tile >> 3;
  const int row0 = tm * 128, col0 = tn * 128;
  const int tid = threadIdx.x, lane = tid & 63, wid = tid >> 6;
  const int wr = wid >> 1, wc = wid & 1;
  __shared__ u16 As[128 * 32];
  __shared__ u16 Bs[128 * 32];
  const u16* Ab = Q + (size_t)bh * 1024 * 2048 + (size_t)row0 * 2048;
  const u16* Bb = K + (size_t)bh * 1024 * 2048 + (size_t)col0 * 2048;
  f32x4 acc[4][4] = {};
  const int lr = lane >> 2, lc = lane & 3;
  const int scs = lc ^ ((lr >> 1) & 3);          // swizzled source chunk
  const int rsw = ((lane & 15) >> 1) & 3;        // read swizzle

  for (int k0 = 0; k0 < 2048; k0 += 32) {
    __syncthreads();
    const u16* s0 = Ab + (size_t)(wid * 16 + lr) * 2048 + k0 + scs * 8;
    gl2lds16(s0, &As[wid * 512]);
    gl2lds16(s0 + (size_t)64 * 2048, &As[2048 + wid * 512]);
    const u16* s1 = Bb + (size_t)(wid * 16 + lr) * 2048 + k0 + scs * 8;
    gl2lds16(s1, &Bs[wid * 512]);
    gl2lds16(s1 + (size_t)64 * 2048, &Bs[2048 + wid * 512]);
    asm volatile("s_waitcnt vmcnt(0)" ::: "memory");
    __syncthreads();
    bf16x8 a[4], bb[4];
    const int g = lane >> 4;
    const int chp = (g ^ rsw) * 8;
    #pragma unroll
    for (int m = 0; m < 4; ++m)
      a[m] = *(const bf16x8*)&As[(wr * 64 + m * 16 + (lane & 15)) * 32 + chp];
    #pragma unroll
    for (int n = 0; n < 4; ++n)
      bb[n] = *(const bf16x8*)&Bs[(wc * 64 + n * 16 + (lane & 15)) * 32 + chp];
    #pragma unroll
    for (int m = 0; m < 4; ++m)
      #pragma unroll
      for (int n = 0; n < 4; ++n)
        acc[m][n] = __builtin_amdgcn_mfma_f32_16x16x32_bf16(a[m], bb[n], acc[m][n], 0, 0, 0);
  }
  const float scale = 0.02209708691207961f;  // 1/sqrt(2048)
  float* out = ATT + (size_t)bh * 1024 * 1024;
  #pragma unroll
  for (int m = 0; m < 4; ++m) {
    int r = row0 + wr * 64 + m * 16 + ((lane >> 4) << 2);
    #pragma unroll
    for (int n = 0; n < 4; ++n) {
      int cc = col0 + wc * 64 + n * 16 + (lane & 15);
      #pragma unroll
      for (int j = 0; j < 4; ++j)
        out[(size_t)(r + j) * 1024 + cc] = acc[m][n][j] * scale;
    }
  }
}

// ---------------- K2b: VT[bh][dv][s] = V[bh][s][dv] (tiled transpose) ----------------
__global__ __launch_bounds__(256) void k_vt(const u16* __restrict__ V,
                                            u16* __restrict__ VT) {
  const int bh = blockIdx.y;
  const int ts = blockIdx.x & 7, td = blockIdx.x >> 3;
  const int s0 = ts * 128, d0 = td * 128;
  const int tid = threadIdx.x;
  __shared__ u16 T[128 * 128];   // [dv][s], s-chunk XOR-swizzled by (dv>>3)&15
  const u16* Vb = V + (size_t)bh * 1024 * 2048 + (size_t)s0 * 2048 + d0;

  #pragma unroll
  for (int pass = 0; pass < 8; ++pass) {
    int r = pass * 16 + (tid >> 4);      // s-local
    int c8 = (tid & 15) * 8;             // dv-local base
    union { uint4 u; u16 e[8]; } d;
    d.u = *(const uint4*)(Vb + (size_t)r * 2048 + c8);
    int chunk = (r >> 3) ^ ((c8 >> 3) & 15);
    u16* dst = &T[0];
    #pragma unroll
    for (int e = 0; e < 8; ++e)
      dst[(c8 + e) * 128 + chunk * 8 + (r & 7)] = d.e[e];
  }
  __syncthreads();
  u16* VTb = VT + (size_t)bh * 2048 * 1024 + (size_t)d0 * 1024 + s0;
  #pragma unroll
  for (int pass = 0; pass < 8; ++pass) {
    int rd = pass * 16 + (tid >> 4);     // dv-local
    int c8 = (tid & 15) * 8;             // s-local base
    int chunk = (c8 >> 3) ^ ((rd >> 3) & 15);
    bf16x8 v = *(const bf16x8*)&T[rd * 128 + chunk * 8];
    *(bf16x8*)(VTb + (size_t)rd * 1024 + c8) = v;
  }
}

// ---------------- K3: row softmax ----------------
__global__ __launch_bounds__(256) void k_softmax(const float* __restrict__ ATT,
                                                 u16* __restrict__ P) {
  const int row = blockIdx.x;
  const float* a = ATT + (size_t)row * 1024;
  const int tid = threadIdx.x;
  float4 v = *(const float4*)(a + tid * 4);
  float mx = fmaxf(fmaxf(v.x, v.y), fmaxf(v.z, v.w));
  #pragma unroll
  for (int off = 32; off; off >>= 1) mx = fmaxf(mx, __shfl_xor(mx, off, 64));
  __shared__ float red[8];
  if ((tid & 63) == 0) red[tid >> 6] = mx;
  __syncthreads();
  mx = fmaxf(fmaxf(red[0], red[1]), fmaxf(red[2], red[3]));
  float e0 = __expf(v.x - mx), e1 = __expf(v.y - mx);
  float e2 = __expf(v.z - mx), e3 = __expf(v.w - mx);
  float s = e0 + e1 + e2 + e3;
  #pragma unroll
  for (int off = 32; off; off >>= 1) s += __shfl_xor(s, off, 64);
  if ((tid & 63) == 0) red[4 + (tid >> 6)] = s;
  __syncthreads();
  s = red[4] + red[5] + red[6] + red[7];
  float inv = 1.0f / s;
  u16x4 o = { f2bf(e0 * inv), f2bf(e1 * inv), f2bf(e2 * inv), f2bf(e3 * inv) };
  *(u16x4*)(P + (size_t)row * 1024 + tid * 4) = o;
}

// ---------------- K4: Y = P V via VT, write NHWC ----------------
// grid 1024 1-D: bh = wgid&7 (one bh per XCD); tm fastest.
__global__ __launch_bounds__(256) void k_pv(const u16* __restrict__ P,
                                            const u16* __restrict__ VT,
                                            u16* __restrict__ Yn) {
  const int bh = blockIdx.x & 7;
  const int tile = blockIdx.x >> 3;
  const int tm = tile & 7, tn = tile >> 3;
  const int row0 = tm * 128, col0 = tn * 128;
  const int tid = threadIdx.x, lane = tid & 63, wid = tid >> 6;
  const int wr = wid >> 1, wc = wid & 1;
  __shared__ __align__(16) u16 smem[17408];
  u16* As = smem;            // 128*32
  u16* Bs = smem + 4096;     // 128*32
  u16* Ot = smem;            // 128*136 (epilogue reuse)
  const u16* Pb = P + (size_t)bh * 1024 * 1024 + (size_t)row0 * 1024;
  const u16* VTb = VT + (size_t)bh * 2048 * 1024 + (size_t)col0 * 1024;
  f32x4 acc[4][4] = {};
  const int lr = lane >> 2, lc = lane & 3;
  const int scs = lc ^ ((lr >> 1) & 3);
  const int rsw = ((lane & 15) >> 1) & 3;

  for (int k0 = 0; k0 < 1024; k0 += 32) {
    __syncthreads();
    const u16* s0 = Pb + (size_t)(wid * 16 + lr) * 1024 + k0 + scs * 8;
    gl2lds16(s0, &As[wid * 512]);
    gl2lds16(s0 + (size_t)64 * 1024, &As[2048 + wid * 512]);
    const u16* s1 = VTb + (size_t)(wid * 16 + lr) * 1024 + k0 + scs * 8;
    gl2lds16(s1, &Bs[wid * 512]);
    gl2lds16(s1 + (size_t)64 * 1024, &Bs[2048 + wid * 512]);
    asm volatile("s_waitcnt vmcnt(0)" ::: "memory");
    __syncthreads();
    bf16x8 a[4], bb[4];
    const int g = lane >> 4;
    const int chp = (g ^ rsw) * 8;
    #pragma unroll
    for (int m = 0; m < 4; ++m)
      a[m] = *(const bf16x8*)&As[(wr * 64 + m * 16 + (lane & 15)) * 32 + chp];
    #pragma unroll
    for (int n = 0; n < 4; ++n)
      bb[n] = *(const bf16x8*)&Bs[(wc * 64 + n * 16 + (lane & 15)) * 32 + chp];
    #pragma unroll
    for (int m = 0; m < 4; ++m)
      #pragma unroll
      for (int n = 0; n < 4; ++n)
        acc[m][n] = __builtin_amdgcn_mfma_f32_16x16x32_bf16(a[m], bb[n], acc[m][n], 0, 0, 0);
  }

  __syncthreads();
  #pragma unroll
  for (int m = 0; m < 4; ++m) {
    int r0 = wr * 64 + m * 16 + ((lane >> 4) << 2);
    #pragma unroll
    for (int n = 0; n < 4; ++n) {
      int dv = wc * 64 + n * 16 + (lane & 15);
      #pragma unroll
      for (int j = 0; j < 4; ++j)
        Ot[(r0 + j) * 136 + dv] = f2bf(acc[m][n][j]);
    }
  }
  __syncthreads();
  const int b = bh >> 2, head = bh & 3;
  const int pixw0 = tn * 4;
  #pragma unroll
  for (int it = 0; it < 8; ++it) {
    int ci = it * 256 + tid;            // 0..2047
    int sl = ci >> 4;
    int pxl = (ci >> 2) & 3;
    int dc = ci & 3;
    bf16x8 vv = *(const bf16x8*)&Ot[sl * 136 + pxl * 32 + dc * 8];
    int s = row0 + sl, oh = s >> 5, ow = s & 31;
    int pixw = pixw0 + pxl, ph = pixw >> 3, pw = pixw & 7;
    int h = oh * 8 + ph, w2 = ow * 8 + pw;
    size_t gaddr = (((size_t)(b * 256 + h) * 256) + w2) * 128 + head * 32 + dc * 8;
    *(bf16x8*)(Yn + gaddr) = vv;
  }
}

// ---------------- K5: 3x3 reflect conv + bias + LeakyReLU (NHWC in, NCHW fp32 out) ----------------
// grid 256, block 512 (8 waves = o-half x 4 rows). Block = 4 h-rows x 128 w x 128 o.
// WT staged per-tap into LDS double-buffer; areg via swizzled ds_read_b128.
__global__ __launch_bounds__(512, 2) void k_conv(const u16* __restrict__ Yn,
                                                 const u16* __restrict__ WT,
                                                 const float* __restrict__ bo,
                                                 float* __restrict__ out) {
  const int wgid = blockIdx.x;
  const int r7 = wgid & 7;
  const int b = (r7 >> 2) & 1;
  const int w0 = ((r7 >> 1) & 1) * 128;
  const int h0 = ((r7 & 1) * 32 + (wgid >> 3)) * 4;     // 0,4,...,252
  const int tid = threadIdx.x, lane = tid & 63, wid = tid >> 6;
  const int wo_ = wid & 1;           // o-half
  const int wh = wid >> 1;           // row 0..3
  const int g = lane >> 4, l15 = lane & 15;
  __shared__ u16 S[6][136 * 64];     // [row][w-slot 0..135][c-half 64], chunk-swizzled
  __shared__ u16 WTl[2][8192];       // [buf][o 128][chunk-swz 64] = 16KB each
  f32x4 acc[4][8] = {};

  auto stageS = [&](int chalf) {
    for (int g5 = wid; g5 < 102; g5 += 8) {
      int rowi = g5 / 17, grp = g5 % 17;
      int rg = grp * 8 + (lane >> 3);       // 0..135
      int chunk = lane & 7;
      int row = h0 + rowi - 1;
      row = row < 0 ? 1 : (row > 255 ? 254 : row);
      int wsrc = w0 - 1 + rg;
      wsrc = wsrc < 0 ? 1 : (wsrc > 255 ? 254 : wsrc);
      const u16* src = Yn + ((size_t)(b * 256 + row) * 256 + wsrc) * 128 + chalf * 64
                         + ((chunk ^ (rg & 7)) * 8);
      gl2lds16(src, &S[rowi][grp * 512]);
    }
  };
  auto stageWT = [&](int chalf, int tap, int nb) {
    #pragma unroll
    for (int r2 = 0; r2 < 2; ++r2) {
      int g5 = wid + r2 * 8;               // 0..15 (o-block of 8)
      int orow = g5 * 8 + (lane >> 3);
      int csrc = (lane & 7) ^ (lane >> 3); // src chunk pre-swizzled by o&7
      const u16* src = WT + ((size_t)tap * 128 + orow) * 128 + chalf * 64 + csrc * 8;
      gl2lds16(src, &WTl[nb][g5 * 512]);
    }
  };

  int buf = 0;
  stageS(0);
  stageWT(0, 0, 0);
  asm volatile("s_waitcnt vmcnt(0)" ::: "memory");
  __syncthreads();

  #pragma unroll
  for (int chalf = 0; chalf < 2; ++chalf) {
    if (chalf) {
      __syncthreads();                     // WAR: all reads of S/WTl done
      stageS(1);
      stageWT(1, 0, buf ^ 1);
      asm volatile("s_waitcnt vmcnt(0)" ::: "memory");
      __syncthreads();
      buf ^= 1;
    }
    #pragma unroll
    for (int ky = 0; ky < 3; ++ky) {
      #pragma unroll
      for (int kx = 0; kx < 3; ++kx) {
        const int tap = ky * 3 + kx;
        const bool hasNext = (tap < 8);
        if (hasNext) stageWT(chalf, tap + 1, buf ^ 1);
        bf16x8 areg[2][4];
        #pragma unroll
        for (int ckh = 0; ckh < 2; ++ckh)
          #pragma unroll
          for (int m = 0; m < 4; ++m) {
            int o = wo_ * 64 + m * 16 + l15;
            int cc2 = ((ckh << 2) + g) ^ (o & 7);
            areg[ckh][m] = *(const bf16x8*)&WTl[buf][o * 64 + cc2 * 8];
          }
        #pragma unroll
        for (int ckh = 0; ckh < 2; ++ckh) {
          #pragma unroll
          for (int nh = 0; nh < 2; ++nh) {
            bf16x8 bb[4];
            #pragma unroll
            for (int n4 = 0; n4 < 4; ++n4) {
              int p = (nh * 4 + n4) * 16 + l15 + kx;   // 0..130
              int chunk = ((ckh << 2) + g) ^ (p & 7);
              bb[n4] = *(const bf16x8*)&S[wh + ky][p * 64 + chunk * 8];
            }
            #pragma unroll
            for (int m = 0; m < 4; ++m)
              #pragma unroll
              for (int n4 = 0; n4 < 4; ++n4)
                acc[m][nh * 4 + n4] = __builtin_amdgcn_mfma_f32_16x16x32_bf16(
                    areg[ckh][m], bb[n4], acc[m][nh * 4 + n4], 0, 0, 0);
          }
        }
        if (hasNext) {
          asm volatile("s_waitcnt vmcnt(0)" ::: "memory");
          __syncthreads();
          buf ^= 1;
        }
      }
    }
  }
  #pragma unroll
  for (int m = 0; m < 4; ++m) {
    int o0 = wo_ * 64 + m * 16 + (g << 2);
    #pragma unroll
    for (int n = 0; n < 8; ++n) {
      int p = n * 16 + l15;
      #pragma unroll
      for (int j = 0; j < 4; ++j) {
        int o = o0 + j;
        float v = acc[m][n][j] + bo[o];
        v = v > 0.f ? v : 0.2f * v;
        out[(((size_t)b * 128 + o) << 16) + ((h0 + wh) << 8) + w0 + p] = v;
      }
    }
  }
}

extern "C" void kernel_launch(void* const* d_in, const int* in_sizes, int n_in,
                              void* d_out, int out_size, void* d_ws, size_t ws_size,
                              hipStream_t stream) {
  const float* x  = (const float*)d_in[0];
  // d_in[1] = mask: dead code in reference
  const float* wq = (const float*)d_in[2];
  const float* bq = (const float*)d_in[3];
  const float* wk = (const float*)d_in[4];
  const float* bk = (const float*)d_in[5];
  const float* wv = (const float*)d_in[6];
  const float* bv = (const float*)d_in[7];
  const float* wo = (const float*)d_in[8];
  const float* bo = (const float*)d_in[9];

  char* ws = (char*)d_ws;
  u16*   WT   = (u16*)(ws);                                 // 288 KiB
  u16*   WQKV = (u16*)(ws + (size_t)(512 << 10));           // 96 KiB
  u16*   Q   = (u16*)(ws + (size_t)(1  << 20));             // 32 MiB (VT aliases after k_qk)
  u16*   K   = (u16*)(ws + (size_t)(33 << 20));             // 32 MiB
  u16*   V   = (u16*)(ws + (size_t)(65 << 20));             // 32 MiB
  float* ATT = (float*)(ws + (size_t)(97 << 20));           // 32 MiB
  u16*   P   = (u16*)(ws + (size_t)(129 << 20));            // 16 MiB
  u16*   Yn  = (u16*)(ws + (size_t)(145 << 20));            // 32 MiB NHWC
  u16*   VT  = Q;   // reuse Q region: Q dead after k_qk
  float* outp = (float*)d_out;

  k_prep<<<768, 256, 0, stream>>>(wo, wq, wk, wv, WT, WQKV);
  k_qkv<<<dim3(1024, 3), 256, 0, stream>>>(x, WQKV, bq, bk, bv, Q, K, V);
  k_qk<<<512, 256, 0, stream>>>(Q, K, ATT);
  k_vt<<<dim3(128, 8), 256, 0, stream>>>(V, VT);
  k_softmax<<<8192, 256, 0, stream>>>(ATT, P);
  k_pv<<<1024, 256, 0, stream>>>(P, VT, Yn);
  k_conv<<<256, 512, 0, stream>>>(Yn, WT, bo, outp);
}

// Round 16
// 214.429 us; speedup vs baseline: 1.0448x; 1.0448x over previous
//
#include <hip/hip_runtime.h>
#include <hip/hip_bf16.h>
#include <stdint.h>

typedef unsigned short u16;
typedef __attribute__((ext_vector_type(8))) short bf16x8;
typedef __attribute__((ext_vector_type(4))) short bf16x4;
typedef __attribute__((ext_vector_type(4))) float f32x4;
typedef __attribute__((ext_vector_type(4))) unsigned short u16x4;

__device__ __forceinline__ float bf2f(u16 u) {
  union { unsigned i; float f; } c; c.i = ((unsigned)u) << 16; return c.f;
}
__device__ __forceinline__ u16 f2bf(float f) {
  union { float f; unsigned i; } c; c.f = f;
  unsigned r = c.i + 0x7FFFu + ((c.i >> 16) & 1u);
  return (u16)(r >> 16);
}
__device__ __forceinline__ unsigned cvt_pk(float lo, float hi) {
  unsigned r;
  asm("v_cvt_pk_bf16_f32 %0, %1, %2" : "=v"(r) : "v"(lo), "v"(hi));
  return r;
}
__device__ __forceinline__ void gl2lds16(const u16* g, u16* l) {
  __builtin_amdgcn_global_load_lds(
      (const __attribute__((address_space(1))) unsigned int*)(uintptr_t)g,
      (__attribute__((address_space(3))) unsigned int*)(uintptr_t)l,
      16, 0, 0);
}

// ---------------- K0: convert weights to bf16 ----------------
__global__ void k_prep(const float* __restrict__ wo, const float* __restrict__ wq,
                       const float* __restrict__ wk, const float* __restrict__ wv,
                       u16* __restrict__ WT, u16* __restrict__ WQKV) {
  int i = blockIdx.x * 256 + threadIdx.x;
  if (i < 9 * 128 * 128) {
    int c = i & 127;
    int o = (i >> 7) & 127;
    int tap = i >> 14;
    WT[i] = f2bf(wo[((o * 128 + c) * 3 + tap / 3) * 3 + tap % 3]);
  } else {
    int j = i - 9 * 128 * 128;
    if (j < 3 * 16384) {
      int sel = j >> 14, rest = j & 16383;
      const float* w = sel == 0 ? wq : (sel == 1 ? wk : wv);
      WQKV[j] = f2bf(w[rest]);
    }
  }
}

// ---------------- K1: fused QKV 1x1 conv + window scatter ----------------
// grid 1024: blk = b*512 + tw*32 + th. block 256 (4 waves).
// B-fragments (x) loaded DIRECTLY to registers (coalesced 64B channel-slices,
// reused across all 3 sels). LDS = Ot only (34.8 KB). 6 barriers/block.
// Q/K/V layout: [bh][s][d], d = pixw*32 + dph.
__global__ __launch_bounds__(256) void k_qkv(
    const float* __restrict__ x, const u16* __restrict__ WQKV,
    const float* __restrict__ bq, const float* __restrict__ bk,
    const float* __restrict__ bv,
    u16* __restrict__ Q, u16* __restrict__ K, u16* __restrict__ V) {
  const int blk = blockIdx.x;
  const int b = blk >> 9;
  const int t = blk & 511;
  const int th = t & 31, tw = t >> 5;
  const int h0 = th * 8, w0 = tw * 16;
  const int s0 = th * 32 + tw * 2;
  const int tid = threadIdx.x, lane = tid & 63, wid = tid >> 6;
  const int wr = wid >> 1, wc = wid & 1;
  const int g = lane >> 4, l15 = lane & 15;

  __shared__ u16 Ot[128 * 136];       // 34816 B — sole LDS

  // load B fragments to registers: pixel(n) = row h0+wc*4+n, col w0+l15;
  // channels ks*32 + g*8 + e  (element e of bf16x8 = channel offset e)
  bf16x8 bfrag[4][4];
  {
    const float* xb = x + (size_t)b * 8388608 + (size_t)(g * 8) * 65536
                        + (h0 + wc * 4) * 256 + w0 + l15;
    #pragma unroll
    for (int ks = 0; ks < 4; ++ks)
      #pragma unroll
      for (int e2 = 0; e2 < 4; ++e2) {
        const float* pa = xb + (size_t)(ks * 32 + e2 * 2) * 65536;
        const float* pb = pa + 65536;
        #pragma unroll
        for (int n = 0; n < 4; ++n)
          ((unsigned*)&bfrag[ks][n])[e2] = cvt_pk(pa[n * 256], pb[n * 256]);
      }
  }

  for (int sel = 0; sel < 3; ++sel) {
    const u16* w = WQKV + sel * 16384;
    const float* bias = sel == 0 ? bq : (sel == 1 ? bk : bv);
    u16* qkv = sel == 0 ? Q : (sel == 1 ? K : V);

    f32x4 acc[4][4] = {};
    #pragma unroll
    for (int ks = 0; ks < 4; ++ks) {
      bf16x8 a[4];
      #pragma unroll
      for (int m = 0; m < 4; ++m) {
        int o = wr * 64 + m * 16 + l15;
        a[m] = *(const bf16x8*)(w + o * 128 + ks * 32 + g * 8);
      }
      #pragma unroll
      for (int m = 0; m < 4; ++m)
        #pragma unroll
        for (int n = 0; n < 4; ++n)
          acc[m][n] = __builtin_amdgcn_mfma_f32_16x16x32_bf16(a[m], bfrag[ks][n], acc[m][n], 0, 0, 0);
    }

    float4 bias4[4];
    #pragma unroll
    for (int m = 0; m < 4; ++m)
      bias4[m] = *(const float4*)&bias[wr * 64 + m * 16 + g * 4];

    __syncthreads();                  // prev sel's Ot reads done
    #pragma unroll
    for (int m = 0; m < 4; ++m) {
      int o0 = wr * 64 + m * 16 + g * 4;
      #pragma unroll
      for (int n = 0; n < 4; ++n) {
        int p = wc * 64 + n * 16 + l15;
        unsigned r0 = cvt_pk(acc[m][n][0] + bias4[m].x, acc[m][n][1] + bias4[m].y);
        unsigned r1 = cvt_pk(acc[m][n][2] + bias4[m].z, acc[m][n][3] + bias4[m].w);
        unsigned* dp = (unsigned*)&Ot[p * 136 + o0];
        dp[0] = r0; dp[1] = r1;
      }
    }
    __syncthreads();
    // stores: it = head*2+s2; 256 threads cover 64 pixw x 4 dphc = 4KB runs
    #pragma unroll
    for (int it = 0; it < 8; ++it) {
      int head = it >> 1, s2 = it & 1;
      int pixw = tid >> 2;              // 0..63
      int dphc = tid & 3;
      int pl = (pixw >> 3) * 16 + s2 * 8 + (pixw & 7);
      bf16x8 vv = *(const bf16x8*)&Ot[pl * 136 + head * 32 + dphc * 8];
      size_t gaddr = ((size_t)((b * 4 + head) * 1024 + s0 + s2)) * 2048 + pixw * 32 + dphc * 8;
      *(bf16x8*)(qkv + gaddr) = vv;
    }
  }
}

// ---------------- K2: ATT = Q K^T * scale ----------------
// grid 512 1-D: bh = wgid&7 (one bh per XCD); tm = tile&7 fastest.
__global__ __launch_bounds__(256) void k_qk(const u16* __restrict__ Q,
                                            const u16* __restrict__ K,
                                            float* __restrict__ ATT) {
  const int bh = blockIdx.x & 7;
  const int tile = blockIdx.x >> 3;
  const int tm = tile & 7, tn = tile >> 3;
  const int row0 = tm * 128, col0 = tn * 128;
  const int tid = threadIdx.x, lane = tid & 63, wid = tid >> 6;
  const int wr = wid >> 1, wc = wid & 1;
  __shared__ u16 As[128 * 32];
  __shared__ u16 Bs[128 * 32];
  const u16* Ab = Q + (size_t)bh * 1024 * 2048 + (size_t)row0 * 2048;
  const u16* Bb = K + (size_t)bh * 1024 * 2048 + (size_t)col0 * 2048;
  f32x4 acc[4][4] = {};
  const int lr = lane >> 2, lc = lane & 3;
  const int scs = lc ^ ((lr >> 1) & 3);          // swizzled source chunk
  const int rsw = ((lane & 15) >> 1) & 3;        // read swizzle

  for (int k0 = 0; k0 < 2048; k0 += 32) {
    __syncthreads();
    const u16* s0 = Ab + (size_t)(wid * 16 + lr) * 2048 + k0 + scs * 8;
    gl2lds16(s0, &As[wid * 512]);
    gl2lds16(s0 + (size_t)64 * 2048, &As[2048 + wid * 512]);
    const u16* s1 = Bb + (size_t)(wid * 16 + lr) * 2048 + k0 + scs * 8;
    gl2lds16(s1, &Bs[wid * 512]);
    gl2lds16(s1 + (size_t)64 * 2048, &Bs[2048 + wid * 512]);
    asm volatile("s_waitcnt vmcnt(0)" ::: "memory");
    __syncthreads();
    bf16x8 a[4], bb[4];
    const int g = lane >> 4;
    const int chp = (g ^ rsw) * 8;
    #pragma unroll
    for (int m = 0; m < 4; ++m)
      a[m] = *(const bf16x8*)&As[(wr * 64 + m * 16 + (lane & 15)) * 32 + chp];
    #pragma unroll
    for (int n = 0; n < 4; ++n)
      bb[n] = *(const bf16x8*)&Bs[(wc * 64 + n * 16 + (lane & 15)) * 32 + chp];
    #pragma unroll
    for (int m = 0; m < 4; ++m)
      #pragma unroll
      for (int n = 0; n < 4; ++n)
        acc[m][n] = __builtin_amdgcn_mfma_f32_16x16x32_bf16(a[m], bb[n], acc[m][n], 0, 0, 0);
  }
  const float scale = 0.02209708691207961f;  // 1/sqrt(2048)
  float* out = ATT + (size_t)bh * 1024 * 1024;
  #pragma unroll
  for (int m = 0; m < 4; ++m) {
    int r = row0 + wr * 64 + m * 16 + ((lane >> 4) << 2);
    #pragma unroll
    for (int n = 0; n < 4; ++n) {
      int cc = col0 + wc * 64 + n * 16 + (lane & 15);
      #pragma unroll
      for (int j = 0; j < 4; ++j)
        out[(size_t)(r + j) * 1024 + cc] = acc[m][n][j] * scale;
    }
  }
}

// ---------------- K2b: VT[bh][dv][s] = V[bh][s][dv] (tiled transpose) ----------------
__global__ __launch_bounds__(256) void k_vt(const u16* __restrict__ V,
                                            u16* __restrict__ VT) {
  const int bh = blockIdx.y;
  const int ts = blockIdx.x & 7, td = blockIdx.x >> 3;
  const int s0 = ts * 128, d0 = td * 128;
  const int tid = threadIdx.x;
  __shared__ u16 T[128 * 128];   // [dv][s], s-chunk XOR-swizzled by (dv>>3)&15
  const u16* Vb = V + (size_t)bh * 1024 * 2048 + (size_t)s0 * 2048 + d0;

  #pragma unroll
  for (int pass = 0; pass < 8; ++pass) {
    int r = pass * 16 + (tid >> 4);      // s-local
    int c8 = (tid & 15) * 8;             // dv-local base
    union { uint4 u; u16 e[8]; } d;
    d.u = *(const uint4*)(Vb + (size_t)r * 2048 + c8);
    int chunk = (r >> 3) ^ ((c8 >> 3) & 15);
    u16* dst = &T[0];
    #pragma unroll
    for (int e = 0; e < 8; ++e)
      dst[(c8 + e) * 128 + chunk * 8 + (r & 7)] = d.e[e];
  }
  __syncthreads();
  u16* VTb = VT + (size_t)bh * 2048 * 1024 + (size_t)d0 * 1024 + s0;
  #pragma unroll
  for (int pass = 0; pass < 8; ++pass) {
    int rd = pass * 16 + (tid >> 4);     // dv-local
    int c8 = (tid & 15) * 8;             // s-local base
    int chunk = (c8 >> 3) ^ ((rd >> 3) & 15);
    bf16x8 v = *(const bf16x8*)&T[rd * 128 + chunk * 8];
    *(bf16x8*)(VTb + (size_t)rd * 1024 + c8) = v;
  }
}

// ---------------- K3: row softmax ----------------
__global__ __launch_bounds__(256) void k_softmax(const float* __restrict__ ATT,
                                                 u16* __restrict__ P) {
  const int row = blockIdx.x;
  const float* a = ATT + (size_t)row * 1024;
  const int tid = threadIdx.x;
  float4 v = *(const float4*)(a + tid * 4);
  float mx = fmaxf(fmaxf(v.x, v.y), fmaxf(v.z, v.w));
  #pragma unroll
  for (int off = 32; off; off >>= 1) mx = fmaxf(mx, __shfl_xor(mx, off, 64));
  __shared__ float red[8];
  if ((tid & 63) == 0) red[tid >> 6] = mx;
  __syncthreads();
  mx = fmaxf(fmaxf(red[0], red[1]), fmaxf(red[2], red[3]));
  float e0 = __expf(v.x - mx), e1 = __expf(v.y - mx);
  float e2 = __expf(v.z - mx), e3 = __expf(v.w - mx);
  float s = e0 + e1 + e2 + e3;
  #pragma unroll
  for (int off = 32; off; off >>= 1) s += __shfl_xor(s, off, 64);
  if ((tid & 63) == 0) red[4 + (tid >> 6)] = s;
  __syncthreads();
  s = red[4] + red[5] + red[6] + red[7];
  float inv = 1.0f / s;
  u16x4 o = { f2bf(e0 * inv), f2bf(e1 * inv), f2bf(e2 * inv), f2bf(e3 * inv) };
  *(u16x4*)(P + (size_t)row * 1024 + tid * 4) = o;
}

// ---------------- K4: Y = P V via VT, write NHWC ----------------
// grid 1024 1-D: bh = wgid&7 (one bh per XCD); tm fastest.
__global__ __launch_bounds__(256) void k_pv(const u16* __restrict__ P,
                                            const u16* __restrict__ VT,
                                            u16* __restrict__ Yn) {
  const int bh = blockIdx.x & 7;
  const int tile = blockIdx.x >> 3;
  const int tm = tile & 7, tn = tile >> 3;
  const int row0 = tm * 128, col0 = tn * 128;
  const int tid = threadIdx.x, lane = tid & 63, wid = tid >> 6;
  const int wr = wid >> 1, wc = wid & 1;
  __shared__ __align__(16) u16 smem[17408];
  u16* As = smem;            // 128*32
  u16* Bs = smem + 4096;     // 128*32
  u16* Ot = smem;            // 128*136 (epilogue reuse)
  const u16* Pb = P + (size_t)bh * 1024 * 1024 + (size_t)row0 * 1024;
  const u16* VTb = VT + (size_t)bh * 2048 * 1024 + (size_t)col0 * 1024;
  f32x4 acc[4][4] = {};
  const int lr = lane >> 2, lc = lane & 3;
  const int scs = lc ^ ((lr >> 1) & 3);
  const int rsw = ((lane & 15) >> 1) & 3;

  for (int k0 = 0; k0 < 1024; k0 += 32) {
    __syncthreads();
    const u16* s0 = Pb + (size_t)(wid * 16 + lr) * 1024 + k0 + scs * 8;
    gl2lds16(s0, &As[wid * 512]);
    gl2lds16(s0 + (size_t)64 * 1024, &As[2048 + wid * 512]);
    const u16* s1 = VTb + (size_t)(wid * 16 + lr) * 1024 + k0 + scs * 8;
    gl2lds16(s1, &Bs[wid * 512]);
    gl2lds16(s1 + (size_t)64 * 1024, &Bs[2048 + wid * 512]);
    asm volatile("s_waitcnt vmcnt(0)" ::: "memory");
    __syncthreads();
    bf16x8 a[4], bb[4];
    const int g = lane >> 4;
    const int chp = (g ^ rsw) * 8;
    #pragma unroll
    for (int m = 0; m < 4; ++m)
      a[m] = *(const bf16x8*)&As[(wr * 64 + m * 16 + (lane & 15)) * 32 + chp];
    #pragma unroll
    for (int n = 0; n < 4; ++n)
      bb[n] = *(const bf16x8*)&Bs[(wc * 64 + n * 16 + (lane & 15)) * 32 + chp];
    #pragma unroll
    for (int m = 0; m < 4; ++m)
      #pragma unroll
      for (int n = 0; n < 4; ++n)
        acc[m][n] = __builtin_amdgcn_mfma_f32_16x16x32_bf16(a[m], bb[n], acc[m][n], 0, 0, 0);
  }

  __syncthreads();
  #pragma unroll
  for (int m = 0; m < 4; ++m) {
    int r0 = wr * 64 + m * 16 + ((lane >> 4) << 2);
    #pragma unroll
    for (int n = 0; n < 4; ++n) {
      int dv = wc * 64 + n * 16 + (lane & 15);
      #pragma unroll
      for (int j = 0; j < 4; ++j)
        Ot[(r0 + j) * 136 + dv] = f2bf(acc[m][n][j]);
    }
  }
  __syncthreads();
  const int b = bh >> 2, head = bh & 3;
  const int pixw0 = tn * 4;
  #pragma unroll
  for (int it = 0; it < 8; ++it) {
    int ci = it * 256 + tid;            // 0..2047
    int sl = ci >> 4;
    int pxl = (ci >> 2) & 3;
    int dc = ci & 3;
    bf16x8 vv = *(const bf16x8*)&Ot[sl * 136 + pxl * 32 + dc * 8];
    int s = row0 + sl, oh = s >> 5, ow = s & 31;
    int pixw = pixw0 + pxl, ph = pixw >> 3, pw = pixw & 7;
    int h = oh * 8 + ph, w2 = ow * 8 + pw;
    size_t gaddr = (((size_t)(b * 256 + h) * 256) + w2) * 128 + head * 32 + dc * 8;
    *(bf16x8*)(Yn + gaddr) = vv;
  }
}

// ---------------- K5: 3x3 reflect conv + bias + LeakyReLU (NHWC in, NCHW fp32 out) ----------------
// grid 256, block 512 (8 waves = o-half x 4 rows). Block = 4 h-rows x 128 w x 128 o.
// WT staged per-tap into LDS double-buffer; areg via swizzled ds_read_b128.
__global__ __launch_bounds__(512, 2) void k_conv(const u16* __restrict__ Yn,
                                                 const u16* __restrict__ WT,
                                                 const float* __restrict__ bo,
                                                 float* __restrict__ out) {
  const int wgid = blockIdx.x;
  const int r7 = wgid & 7;
  const int b = (r7 >> 2) & 1;
  const int w0 = ((r7 >> 1) & 1) * 128;
  const int h0 = ((r7 & 1) * 32 + (wgid >> 3)) * 4;     // 0,4,...,252
  const int tid = threadIdx.x, lane = tid & 63, wid = tid >> 6;
  const int wo_ = wid & 1;           // o-half
  const int wh = wid >> 1;           // row 0..3
  const int g = lane >> 4, l15 = lane & 15;
  __shared__ u16 S[6][136 * 64];     // [row][w-slot 0..135][c-half 64], chunk-swizzled
  __shared__ u16 WTl[2][8192];       // [buf][o 128][chunk-swz 64] = 16KB each
  f32x4 acc[4][8] = {};

  auto stageS = [&](int chalf) {
    for (int g5 = wid; g5 < 102; g5 += 8) {
      int rowi = g5 / 17, grp = g5 % 17;
      int rg = grp * 8 + (lane >> 3);       // 0..135
      int chunk = lane & 7;
      int row = h0 + rowi - 1;
      row = row < 0 ? 1 : (row > 255 ? 254 : row);
      int wsrc = w0 - 1 + rg;
      wsrc = wsrc < 0 ? 1 : (wsrc > 255 ? 254 : wsrc);
      const u16* src = Yn + ((size_t)(b * 256 + row) * 256 + wsrc) * 128 + chalf * 64
                         + ((chunk ^ (rg & 7)) * 8);
      gl2lds16(src, &S[rowi][grp * 512]);
    }
  };
  auto stageWT = [&](int chalf, int tap, int nb) {
    #pragma unroll
    for (int r2 = 0; r2 < 2; ++r2) {
      int g5 = wid + r2 * 8;               // 0..15 (o-block of 8)
      int orow = g5 * 8 + (lane >> 3);
      int csrc = (lane & 7) ^ (lane >> 3); // src chunk pre-swizzled by o&7
      const u16* src = WT + ((size_t)tap * 128 + orow) * 128 + chalf * 64 + csrc * 8;
      gl2lds16(src, &WTl[nb][g5 * 512]);
    }
  };

  int buf = 0;
  stageS(0);
  stageWT(0, 0, 0);
  asm volatile("s_waitcnt vmcnt(0)" ::: "memory");
  __syncthreads();

  #pragma unroll
  for (int chalf = 0; chalf < 2; ++chalf) {
    if (chalf) {
      __syncthreads();                     // WAR: all reads of S/WTl done
      stageS(1);
      stageWT(1, 0, buf ^ 1);
      asm volatile("s_waitcnt vmcnt(0)" ::: "memory");
      __syncthreads();
      buf ^= 1;
    }
    #pragma unroll
    for (int ky = 0; ky < 3; ++ky) {
      #pragma unroll
      for (int kx = 0; kx < 3; ++kx) {
        const int tap = ky * 3 + kx;
        const bool hasNext = (tap < 8);
        if (hasNext) stageWT(chalf, tap + 1, buf ^ 1);
        bf16x8 areg[2][4];
        #pragma unroll
        for (int ckh = 0; ckh < 2; ++ckh)
          #pragma unroll
          for (int m = 0; m < 4; ++m) {
            int o = wo_ * 64 + m * 16 + l15;
            int cc2 = ((ckh << 2) + g) ^ (o & 7);
            areg[ckh][m] = *(const bf16x8*)&WTl[buf][o * 64 + cc2 * 8];
          }
        #pragma unroll
        for (int ckh = 0; ckh < 2; ++ckh) {
          #pragma unroll
          for (int nh = 0; nh < 2; ++nh) {
            bf16x8 bb[4];
            #pragma unroll
            for (int n4 = 0; n4 < 4; ++n4) {
              int p = (nh * 4 + n4) * 16 + l15 + kx;   // 0..130
              int chunk = ((ckh << 2) + g) ^ (p & 7);
              bb[n4] = *(const bf16x8*)&S[wh + ky][p * 64 + chunk * 8];
            }
            #pragma unroll
            for (int m = 0; m < 4; ++m)
              #pragma unroll
              for (int n4 = 0; n4 < 4; ++n4)
                acc[m][nh * 4 + n4] = __builtin_amdgcn_mfma_f32_16x16x32_bf16(
                    areg[ckh][m], bb[n4], acc[m][nh * 4 + n4], 0, 0, 0);
          }
        }
        if (hasNext) {
          asm volatile("s_waitcnt vmcnt(0)" ::: "memory");
          __syncthreads();
          buf ^= 1;
        }
      }
    }
  }
  #pragma unroll
  for (int m = 0; m < 4; ++m) {
    int o0 = wo_ * 64 + m * 16 + (g << 2);
    #pragma unroll
    for (int n = 0; n < 8; ++n) {
      int p = n * 16 + l15;
      #pragma unroll
      for (int j = 0; j < 4; ++j) {
        int o = o0 + j;
        float v = acc[m][n][j] + bo[o];
        v = v > 0.f ? v : 0.2f * v;
        out[(((size_t)b * 128 + o) << 16) + ((h0 + wh) << 8) + w0 + p] = v;
      }
    }
  }
}

extern "C" void kernel_launch(void* const* d_in, const int* in_sizes, int n_in,
                              void* d_out, int out_size, void* d_ws, size_t ws_size,
                              hipStream_t stream) {
  const float* x  = (const float*)d_in[0];
  // d_in[1] = mask: dead code in reference
  const float* wq = (const float*)d_in[2];
  const float* bq = (const float*)d_in[3];
  const float* wk = (const float*)d_in[4];
  const float* bk = (const float*)d_in[5];
  const float* wv = (const float*)d_in[6];
  const float* bv = (const float*)d_in[7];
  const float* wo = (const float*)d_in[8];
  const float* bo = (const float*)d_in[9];

  char* ws = (char*)d_ws;
  u16*   WT   = (u16*)(ws);                                 // 288 KiB
  u16*   WQKV = (u16*)(ws + (size_t)(512 << 10));           // 96 KiB
  u16*   Q   = (u16*)(ws + (size_t)(1  << 20));             // 32 MiB (VT aliases after k_qk)
  u16*   K   = (u16*)(ws + (size_t)(33 << 20));             // 32 MiB
  u16*   V   = (u16*)(ws + (size_t)(65 << 20));             // 32 MiB
  float* ATT = (float*)(ws + (size_t)(97 << 20));           // 32 MiB
  u16*   P   = (u16*)(ws + (size_t)(129 << 20));            // 16 MiB
  u16*   Yn  = (u16*)(ws + (size_t)(145 << 20));            // 32 MiB NHWC
  u16*   VT  = Q;   // reuse Q region: Q dead after k_qk
  float* outp = (float*)d_out;

  k_prep<<<768, 256, 0, stream>>>(wo, wq, wk, wv, WT, WQKV);
  k_qkv<<<1024, 256, 0, stream>>>(x, WQKV, bq, bk, bv, Q, K, V);
  k_qk<<<512, 256, 0, stream>>>(Q, K, ATT);
  k_vt<<<dim3(128, 8), 256, 0, stream>>>(V, VT);
  k_softmax<<<8192, 256, 0, stream>>>(ATT, P);
  k_pv<<<1024, 256, 0, stream>>>(P, VT, Yn);
  k_conv<<<256, 512, 0, stream>>>(Yn, WT, bo, outp);
}

// Round 17
// 212.881 us; speedup vs baseline: 1.0524x; 1.0073x over previous
//
#include <hip/hip_runtime.h>
#include <hip/hip_bf16.h>
#include <stdint.h>

typedef unsigned short u16;
typedef __attribute__((ext_vector_type(8))) short bf16x8;
typedef __attribute__((ext_vector_type(4))) short bf16x4;
typedef __attribute__((ext_vector_type(4))) float f32x4;
typedef __attribute__((ext_vector_type(4))) unsigned short u16x4;

__device__ __forceinline__ float bf2f(u16 u) {
  union { unsigned i; float f; } c; c.i = ((unsigned)u) << 16; return c.f;
}
__device__ __forceinline__ u16 f2bf(float f) {
  union { float f; unsigned i; } c; c.f = f;
  unsigned r = c.i + 0x7FFFu + ((c.i >> 16) & 1u);
  return (u16)(r >> 16);
}
__device__ __forceinline__ unsigned cvt_pk(float lo, float hi) {
  unsigned r;
  asm("v_cvt_pk_bf16_f32 %0, %1, %2" : "=v"(r) : "v"(lo), "v"(hi));
  return r;
}
__device__ __forceinline__ void gl2lds16(const u16* g, u16* l) {
  __builtin_amdgcn_global_load_lds(
      (const __attribute__((address_space(1))) unsigned int*)(uintptr_t)g,
      (__attribute__((address_space(3))) unsigned int*)(uintptr_t)l,
      16, 0, 0);
}

// ---------------- K0: convert weights to bf16 ----------------
__global__ void k_prep(const float* __restrict__ wo, const float* __restrict__ wq,
                       const float* __restrict__ wk, const float* __restrict__ wv,
                       u16* __restrict__ WT, u16* __restrict__ WQKV) {
  int i = blockIdx.x * 256 + threadIdx.x;
  if (i < 9 * 128 * 128) {
    int c = i & 127;
    int o = (i >> 7) & 127;
    int tap = i >> 14;
    WT[i] = f2bf(wo[((o * 128 + c) * 3 + tap / 3) * 3 + tap % 3]);
  } else {
    int j = i - 9 * 128 * 128;
    if (j < 3 * 16384) {
      int sel = j >> 14, rest = j & 16383;
      const float* w = sel == 0 ? wq : (sel == 1 ? wk : wv);
      WQKV[j] = f2bf(w[rest]);
    }
  }
}

// ---------------- K1: fused QKV 1x1 conv + window scatter ----------------
// grid 1024: blk = b*512 + tw*32 + th. block 256 (4 waves).
// B-fragments (x) loaded DIRECTLY to registers; LDS = Ot only (34.8 KB).
// Q/K/V layout: [bh][s][d], d = pixw*32 + dph.
__global__ __launch_bounds__(256) void k_qkv(
    const float* __restrict__ x, const u16* __restrict__ WQKV,
    const float* __restrict__ bq, const float* __restrict__ bk,
    const float* __restrict__ bv,
    u16* __restrict__ Q, u16* __restrict__ K, u16* __restrict__ V) {
  const int blk = blockIdx.x;
  const int b = blk >> 9;
  const int t = blk & 511;
  const int th = t & 31, tw = t >> 5;
  const int h0 = th * 8, w0 = tw * 16;
  const int s0 = th * 32 + tw * 2;
  const int tid = threadIdx.x, lane = tid & 63, wid = tid >> 6;
  const int wr = wid >> 1, wc = wid & 1;
  const int g = lane >> 4, l15 = lane & 15;

  __shared__ u16 Ot[128 * 136];       // 34816 B — sole LDS

  bf16x8 bfrag[4][4];
  {
    const float* xb = x + (size_t)b * 8388608 + (size_t)(g * 8) * 65536
                        + (h0 + wc * 4) * 256 + w0 + l15;
    #pragma unroll
    for (int ks = 0; ks < 4; ++ks)
      #pragma unroll
      for (int e2 = 0; e2 < 4; ++e2) {
        const float* pa = xb + (size_t)(ks * 32 + e2 * 2) * 65536;
        const float* pb = pa + 65536;
        #pragma unroll
        for (int n = 0; n < 4; ++n)
          ((unsigned*)&bfrag[ks][n])[e2] = cvt_pk(pa[n * 256], pb[n * 256]);
      }
  }

  for (int sel = 0; sel < 3; ++sel) {
    const u16* w = WQKV + sel * 16384;
    const float* bias = sel == 0 ? bq : (sel == 1 ? bk : bv);
    u16* qkv = sel == 0 ? Q : (sel == 1 ? K : V);

    f32x4 acc[4][4] = {};
    #pragma unroll
    for (int ks = 0; ks < 4; ++ks) {
      bf16x8 a[4];
      #pragma unroll
      for (int m = 0; m < 4; ++m) {
        int o = wr * 64 + m * 16 + l15;
        a[m] = *(const bf16x8*)(w + o * 128 + ks * 32 + g * 8);
      }
      #pragma unroll
      for (int m = 0; m < 4; ++m)
        #pragma unroll
        for (int n = 0; n < 4; ++n)
          acc[m][n] = __builtin_amdgcn_mfma_f32_16x16x32_bf16(a[m], bfrag[ks][n], acc[m][n], 0, 0, 0);
    }

    float4 bias4[4];
    #pragma unroll
    for (int m = 0; m < 4; ++m)
      bias4[m] = *(const float4*)&bias[wr * 64 + m * 16 + g * 4];

    __syncthreads();
    #pragma unroll
    for (int m = 0; m < 4; ++m) {
      int o0 = wr * 64 + m * 16 + g * 4;
      #pragma unroll
      for (int n = 0; n < 4; ++n) {
        int p = wc * 64 + n * 16 + l15;
        unsigned r0 = cvt_pk(acc[m][n][0] + bias4[m].x, acc[m][n][1] + bias4[m].y);
        unsigned r1 = cvt_pk(acc[m][n][2] + bias4[m].z, acc[m][n][3] + bias4[m].w);
        unsigned* dp = (unsigned*)&Ot[p * 136 + o0];
        dp[0] = r0; dp[1] = r1;
      }
    }
    __syncthreads();
    #pragma unroll
    for (int it = 0; it < 8; ++it) {
      int head = it >> 1, s2 = it & 1;
      int pixw = tid >> 2;
      int dphc = tid & 3;
      int pl = (pixw >> 3) * 16 + s2 * 8 + (pixw & 7);
      bf16x8 vv = *(const bf16x8*)&Ot[pl * 136 + head * 32 + dphc * 8];
      size_t gaddr = ((size_t)((b * 4 + head) * 1024 + s0 + s2)) * 2048 + pixw * 32 + dphc * 8;
      *(bf16x8*)(qkv + gaddr) = vv;
    }
  }
}

// ---------------- K2: fused {ATT = Q K^T * scale} + {VT transpose} ----------------
// grid 1536: wgid<512 -> qk (bh = wgid&7, tm fastest, dbuf staging);
//            wgid>=512 -> vt (idx = wgid-512, bh = idx&7).
__global__ __launch_bounds__(256) void k_qkvt(const u16* __restrict__ Q,
                                              const u16* __restrict__ K,
                                              float* __restrict__ ATT,
                                              const u16* __restrict__ V,
                                              u16* __restrict__ VT) {
  __shared__ __align__(16) u16 smem[16384];   // 32 KB: qk dbuf / vt tile
  const int tid = threadIdx.x, lane = tid & 63, wid = tid >> 6;

  if (blockIdx.x < 512) {
    const int bh = blockIdx.x & 7;
    const int tile = blockIdx.x >> 3;
    const int tm = tile & 7, tn = tile >> 3;
    const int row0 = tm * 128, col0 = tn * 128;
    const int wr = wid >> 1, wc = wid & 1;
    const u16* Ab = Q + (size_t)bh * 1024 * 2048 + (size_t)row0 * 2048;
    const u16* Bb = K + (size_t)bh * 1024 * 2048 + (size_t)col0 * 2048;
    f32x4 acc[4][4] = {};
    const int lr = lane >> 2, lc = lane & 3;
    const int scs = lc ^ ((lr >> 1) & 3);
    const int rsw = ((lane & 15) >> 1) & 3;

    auto stage = [&](int k0, int bf) {
      u16* As = smem + bf * 8192;
      u16* Bs = smem + 4096 + bf * 8192;
      const u16* s0 = Ab + (size_t)(wid * 16 + lr) * 2048 + k0 + scs * 8;
      gl2lds16(s0, &As[wid * 512]);
      gl2lds16(s0 + (size_t)64 * 2048, &As[2048 + wid * 512]);
      const u16* s1 = Bb + (size_t)(wid * 16 + lr) * 2048 + k0 + scs * 8;
      gl2lds16(s1, &Bs[wid * 512]);
      gl2lds16(s1 + (size_t)64 * 2048, &Bs[2048 + wid * 512]);
    };

    stage(0, 0);
    asm volatile("s_waitcnt vmcnt(0)" ::: "memory");
    __syncthreads();
    int cur = 0;
    for (int k0 = 0; k0 < 2048; k0 += 32) {
      if (k0 + 32 < 2048) stage(k0 + 32, cur ^ 1);
      const u16* As = smem + cur * 8192;
      const u16* Bs = smem + 4096 + cur * 8192;
      bf16x8 a[4], bb[4];
      const int g = lane >> 4;
      const int chp = (g ^ rsw) * 8;
      #pragma unroll
      for (int m = 0; m < 4; ++m)
        a[m] = *(const bf16x8*)&As[(wr * 64 + m * 16 + (lane & 15)) * 32 + chp];
      #pragma unroll
      for (int n = 0; n < 4; ++n)
        bb[n] = *(const bf16x8*)&Bs[(wc * 64 + n * 16 + (lane & 15)) * 32 + chp];
      #pragma unroll
      for (int m = 0; m < 4; ++m)
        #pragma unroll
        for (int n = 0; n < 4; ++n)
          acc[m][n] = __builtin_amdgcn_mfma_f32_16x16x32_bf16(a[m], bb[n], acc[m][n], 0, 0, 0);
      asm volatile("s_waitcnt vmcnt(0)" ::: "memory");
      __syncthreads();
      cur ^= 1;
    }
    const float scale = 0.02209708691207961f;  // 1/sqrt(2048)
    float* out = ATT + (size_t)bh * 1024 * 1024;
    #pragma unroll
    for (int m = 0; m < 4; ++m) {
      int r = row0 + wr * 64 + m * 16 + ((lane >> 4) << 2);
      #pragma unroll
      for (int n = 0; n < 4; ++n) {
        int cc = col0 + wc * 64 + n * 16 + (lane & 15);
        #pragma unroll
        for (int j = 0; j < 4; ++j)
          out[(size_t)(r + j) * 1024 + cc] = acc[m][n][j] * scale;
      }
    }
  } else {
    const int idx = blockIdx.x - 512;
    const int bh = idx & 7;
    const int t2 = idx >> 3;
    const int ts = t2 & 7, td = t2 >> 3;
    const int s0 = ts * 128, d0 = td * 128;
    u16* T = smem;                 // [dv][s], s-chunk XOR-swizzled
    const u16* Vb = V + (size_t)bh * 1024 * 2048 + (size_t)s0 * 2048 + d0;

    #pragma unroll
    for (int pass = 0; pass < 8; ++pass) {
      int r = pass * 16 + (tid >> 4);
      int c8 = (tid & 15) * 8;
      union { uint4 u; u16 e[8]; } d;
      d.u = *(const uint4*)(Vb + (size_t)r * 2048 + c8);
      int chunk = (r >> 3) ^ ((c8 >> 3) & 15);
      #pragma unroll
      for (int e = 0; e < 8; ++e)
        T[(c8 + e) * 128 + chunk * 8 + (r & 7)] = d.e[e];
    }
    __syncthreads();
    u16* VTb = VT + (size_t)bh * 2048 * 1024 + (size_t)d0 * 1024 + s0;
    #pragma unroll
    for (int pass = 0; pass < 8; ++pass) {
      int rd = pass * 16 + (tid >> 4);
      int c8 = (tid & 15) * 8;
      int chunk = (c8 >> 3) ^ ((rd >> 3) & 15);
      bf16x8 v = *(const bf16x8*)&T[rd * 128 + chunk * 8];
      *(bf16x8*)(VTb + (size_t)rd * 1024 + c8) = v;
    }
  }
}

// ---------------- K3: row softmax ----------------
__global__ __launch_bounds__(256) void k_softmax(const float* __restrict__ ATT,
                                                 u16* __restrict__ P) {
  const int row = blockIdx.x;
  const float* a = ATT + (size_t)row * 1024;
  const int tid = threadIdx.x;
  float4 v = *(const float4*)(a + tid * 4);
  float mx = fmaxf(fmaxf(v.x, v.y), fmaxf(v.z, v.w));
  #pragma unroll
  for (int off = 32; off; off >>= 1) mx = fmaxf(mx, __shfl_xor(mx, off, 64));
  __shared__ float red[8];
  if ((tid & 63) == 0) red[tid >> 6] = mx;
  __syncthreads();
  mx = fmaxf(fmaxf(red[0], red[1]), fmaxf(red[2], red[3]));
  float e0 = __expf(v.x - mx), e1 = __expf(v.y - mx);
  float e2 = __expf(v.z - mx), e3 = __expf(v.w - mx);
  float s = e0 + e1 + e2 + e3;
  #pragma unroll
  for (int off = 32; off; off >>= 1) s += __shfl_xor(s, off, 64);
  if ((tid & 63) == 0) red[4 + (tid >> 6)] = s;
  __syncthreads();
  s = red[4] + red[5] + red[6] + red[7];
  float inv = 1.0f / s;
  u16x4 o = { f2bf(e0 * inv), f2bf(e1 * inv), f2bf(e2 * inv), f2bf(e3 * inv) };
  *(u16x4*)(P + (size_t)row * 1024 + tid * 4) = o;
}

// ---------------- K4: Y = P V via VT, write NHWC ----------------
// grid 1024 1-D: bh = wgid&7; tm fastest. Double-buffered staging.
__global__ __launch_bounds__(256) void k_pv(const u16* __restrict__ P,
                                            const u16* __restrict__ VT,
                                            u16* __restrict__ Yn) {
  const int bh = blockIdx.x & 7;
  const int tile = blockIdx.x >> 3;
  const int tm = tile & 7, tn = tile >> 3;
  const int row0 = tm * 128, col0 = tn * 128;
  const int tid = threadIdx.x, lane = tid & 63, wid = tid >> 6;
  const int wr = wid >> 1, wc = wid & 1;
  __shared__ __align__(16) u16 smem[17408];   // dbuf 32KB; Ot 34.8KB aliased
  u16* Ot = smem;
  const u16* Pb = P + (size_t)bh * 1024 * 1024 + (size_t)row0 * 1024;
  const u16* VTb = VT + (size_t)bh * 2048 * 1024 + (size_t)col0 * 1024;
  f32x4 acc[4][4] = {};
  const int lr = lane >> 2, lc = lane & 3;
  const int scs = lc ^ ((lr >> 1) & 3);
  const int rsw = ((lane & 15) >> 1) & 3;

  auto stage = [&](int k0, int bf) {
    u16* As = smem + bf * 8192;
    u16* Bs = smem + 4096 + bf * 8192;
    const u16* s0 = Pb + (size_t)(wid * 16 + lr) * 1024 + k0 + scs * 8;
    gl2lds16(s0, &As[wid * 512]);
    gl2lds16(s0 + (size_t)64 * 1024, &As[2048 + wid * 512]);
    const u16* s1 = VTb + (size_t)(wid * 16 + lr) * 1024 + k0 + scs * 8;
    gl2lds16(s1, &Bs[wid * 512]);
    gl2lds16(s1 + (size_t)64 * 1024, &Bs[2048 + wid * 512]);
  };

  stage(0, 0);
  asm volatile("s_waitcnt vmcnt(0)" ::: "memory");
  __syncthreads();
  int cur = 0;
  for (int k0 = 0; k0 < 1024; k0 += 32) {
    if (k0 + 32 < 1024) stage(k0 + 32, cur ^ 1);
    const u16* As = smem + cur * 8192;
    const u16* Bs = smem + 4096 + cur * 8192;
    bf16x8 a[4], bb[4];
    const int g = lane >> 4;
    const int chp = (g ^ rsw) * 8;
    #pragma unroll
    for (int m = 0; m < 4; ++m)
      a[m] = *(const bf16x8*)&As[(wr * 64 + m * 16 + (lane & 15)) * 32 + chp];
    #pragma unroll
    for (int n = 0; n < 4; ++n)
      bb[n] = *(const bf16x8*)&Bs[(wc * 64 + n * 16 + (lane & 15)) * 32 + chp];
    #pragma unroll
    for (int m = 0; m < 4; ++m)
      #pragma unroll
      for (int n = 0; n < 4; ++n)
        acc[m][n] = __builtin_amdgcn_mfma_f32_16x16x32_bf16(a[m], bb[n], acc[m][n], 0, 0, 0);
    asm volatile("s_waitcnt vmcnt(0)" ::: "memory");
    __syncthreads();
    cur ^= 1;
  }

  #pragma unroll
  for (int m = 0; m < 4; ++m) {
    int r0 = wr * 64 + m * 16 + ((lane >> 4) << 2);
    #pragma unroll
    for (int n = 0; n < 4; ++n) {
      int dv = wc * 64 + n * 16 + (lane & 15);
      #pragma unroll
      for (int j = 0; j < 4; ++j)
        Ot[(r0 + j) * 136 + dv] = f2bf(acc[m][n][j]);
    }
  }
  __syncthreads();
  const int b = bh >> 2, head = bh & 3;
  const int pixw0 = tn * 4;
  #pragma unroll
  for (int it = 0; it < 8; ++it) {
    int ci = it * 256 + tid;
    int sl = ci >> 4;
    int pxl = (ci >> 2) & 3;
    int dc = ci & 3;
    bf16x8 vv = *(const bf16x8*)&Ot[sl * 136 + pxl * 32 + dc * 8];
    int s = row0 + sl, oh = s >> 5, ow = s & 31;
    int pixw = pixw0 + pxl, ph = pixw >> 3, pw = pixw & 7;
    int h = oh * 8 + ph, w2 = ow * 8 + pw;
    size_t gaddr = (((size_t)(b * 256 + h) * 256) + w2) * 128 + head * 32 + dc * 8;
    *(bf16x8*)(Yn + gaddr) = vv;
  }
}

// ---------------- K5: 3x3 reflect conv + bias + LeakyReLU (NHWC in, NCHW fp32 out) ----------------
__global__ __launch_bounds__(512, 2) void k_conv(const u16* __restrict__ Yn,
                                                 const u16* __restrict__ WT,
                                                 const float* __restrict__ bo,
                                                 float* __restrict__ out) {
  const int wgid = blockIdx.x;
  const int r7 = wgid & 7;
  const int b = (r7 >> 2) & 1;
  const int w0 = ((r7 >> 1) & 1) * 128;
  const int h0 = ((r7 & 1) * 32 + (wgid >> 3)) * 4;     // 0,4,...,252
  const int tid = threadIdx.x, lane = tid & 63, wid = tid >> 6;
  const int wo_ = wid & 1;
  const int wh = wid >> 1;
  const int g = lane >> 4, l15 = lane & 15;
  __shared__ u16 S[6][136 * 64];
  __shared__ u16 WTl[2][8192];
  f32x4 acc[4][8] = {};

  auto stageS = [&](int chalf) {
    for (int g5 = wid; g5 < 102; g5 += 8) {
      int rowi = g5 / 17, grp = g5 % 17;
      int rg = grp * 8 + (lane >> 3);
      int chunk = lane & 7;
      int row = h0 + rowi - 1;
      row = row < 0 ? 1 : (row > 255 ? 254 : row);
      int wsrc = w0 - 1 + rg;
      wsrc = wsrc < 0 ? 1 : (wsrc > 255 ? 254 : wsrc);
      const u16* src = Yn + ((size_t)(b * 256 + row) * 256 + wsrc) * 128 + chalf * 64
                         + ((chunk ^ (rg & 7)) * 8);
      gl2lds16(src, &S[rowi][grp * 512]);
    }
  };
  auto stageWT = [&](int chalf, int tap, int nb) {
    #pragma unroll
    for (int r2 = 0; r2 < 2; ++r2) {
      int g5 = wid + r2 * 8;
      int orow = g5 * 8 + (lane >> 3);
      int csrc = (lane & 7) ^ (lane >> 3);
      const u16* src = WT + ((size_t)tap * 128 + orow) * 128 + chalf * 64 + csrc * 8;
      gl2lds16(src, &WTl[nb][g5 * 512]);
    }
  };

  int buf = 0;
  stageS(0);
  stageWT(0, 0, 0);
  asm volatile("s_waitcnt vmcnt(0)" ::: "memory");
  __syncthreads();

  #pragma unroll
  for (int chalf = 0; chalf < 2; ++chalf) {
    if (chalf) {
      __syncthreads();
      stageS(1);
      stageWT(1, 0, buf ^ 1);
      asm volatile("s_waitcnt vmcnt(0)" ::: "memory");
      __syncthreads();
      buf ^= 1;
    }
    #pragma unroll
    for (int ky = 0; ky < 3; ++ky) {
      #pragma unroll
      for (int kx = 0; kx < 3; ++kx) {
        const int tap = ky * 3 + kx;
        const bool hasNext = (tap < 8);
        if (hasNext) stageWT(chalf, tap + 1, buf ^ 1);
        bf16x8 areg[2][4];
        #pragma unroll
        for (int ckh = 0; ckh < 2; ++ckh)
          #pragma unroll
          for (int m = 0; m < 4; ++m) {
            int o = wo_ * 64 + m * 16 + l15;
            int cc2 = ((ckh << 2) + g) ^ (o & 7);
            areg[ckh][m] = *(const bf16x8*)&WTl[buf][o * 64 + cc2 * 8];
          }
        #pragma unroll
        for (int ckh = 0; ckh < 2; ++ckh) {
          #pragma unroll
          for (int nh = 0; nh < 2; ++nh) {
            bf16x8 bb[4];
            #pragma unroll
            for (int n4 = 0; n4 < 4; ++n4) {
              int p = (nh * 4 + n4) * 16 + l15 + kx;
              int chunk = ((ckh << 2) + g) ^ (p & 7);
              bb[n4] = *(const bf16x8*)&S[wh + ky][p * 64 + chunk * 8];
            }
            #pragma unroll
            for (int m = 0; m < 4; ++m)
              #pragma unroll
              for (int n4 = 0; n4 < 4; ++n4)
                acc[m][nh * 4 + n4] = __builtin_amdgcn_mfma_f32_16x16x32_bf16(
                    areg[ckh][m], bb[n4], acc[m][nh * 4 + n4], 0, 0, 0);
          }
        }
        if (hasNext) {
          asm volatile("s_waitcnt vmcnt(0)" ::: "memory");
          __syncthreads();
          buf ^= 1;
        }
      }
    }
  }
  #pragma unroll
  for (int m = 0; m < 4; ++m) {
    int o0 = wo_ * 64 + m * 16 + (g << 2);
    #pragma unroll
    for (int n = 0; n < 8; ++n) {
      int p = n * 16 + l15;
      #pragma unroll
      for (int j = 0; j < 4; ++j) {
        int o = o0 + j;
        float v = acc[m][n][j] + bo[o];
        v = v > 0.f ? v : 0.2f * v;
        out[(((size_t)b * 128 + o) << 16) + ((h0 + wh) << 8) + w0 + p] = v;
      }
    }
  }
}

extern "C" void kernel_launch(void* const* d_in, const int* in_sizes, int n_in,
                              void* d_out, int out_size, void* d_ws, size_t ws_size,
                              hipStream_t stream) {
  const float* x  = (const float*)d_in[0];
  // d_in[1] = mask: dead code in reference
  const float* wq = (const float*)d_in[2];
  const float* bq = (const float*)d_in[3];
  const float* wk = (const float*)d_in[4];
  const float* bk = (const float*)d_in[5];
  const float* wv = (const float*)d_in[6];
  const float* bv = (const float*)d_in[7];
  const float* wo = (const float*)d_in[8];
  const float* bo = (const float*)d_in[9];

  char* ws = (char*)d_ws;
  u16*   WT   = (u16*)(ws);                                 // 288 KiB
  u16*   WQKV = (u16*)(ws + (size_t)(512 << 10));           // 96 KiB
  u16*   Q   = (u16*)(ws + (size_t)(1  << 20));             // 32 MiB
  u16*   K   = (u16*)(ws + (size_t)(33 << 20));             // 32 MiB
  u16*   V   = (u16*)(ws + (size_t)(65 << 20));             // 32 MiB
  float* ATT = (float*)(ws + (size_t)(97 << 20));           // 32 MiB
  u16*   P   = (u16*)(ws + (size_t)(129 << 20));            // 16 MiB
  u16*   Yn  = (u16*)(ws + (size_t)(145 << 20));            // 32 MiB NHWC
  u16*   VT  = (u16*)(ws + (size_t)(177 << 20));            // 32 MiB [bh][d][s]
  float* outp = (float*)d_out;

  k_prep<<<768, 256, 0, stream>>>(wo, wq, wk, wv, WT, WQKV);
  k_qkv<<<1024, 256, 0, stream>>>(x, WQKV, bq, bk, bv, Q, K, V);
  k_qkvt<<<1536, 256, 0, stream>>>(Q, K, ATT, V, VT);
  k_softmax<<<8192, 256, 0, stream>>>(ATT, P);
  k_pv<<<1024, 256, 0, stream>>>(P, VT, Yn);
  k_conv<<<256, 512, 0, stream>>>(Yn, WT, bo, outp);
}

// Round 18
// 209.947 us; speedup vs baseline: 1.0671x; 1.0140x over previous
//
#include <hip/hip_runtime.h>
#include <hip/hip_bf16.h>
#include <stdint.h>

typedef unsigned short u16;
typedef __attribute__((ext_vector_type(8))) short bf16x8;
typedef __attribute__((ext_vector_type(4))) short bf16x4;
typedef __attribute__((ext_vector_type(4))) float f32x4;
typedef __attribute__((ext_vector_type(4))) unsigned short u16x4;

__device__ __forceinline__ float bf2f(u16 u) {
  union { unsigned i; float f; } c; c.i = ((unsigned)u) << 16; return c.f;
}
__device__ __forceinline__ u16 f2bf(float f) {
  union { float f; unsigned i; } c; c.f = f;
  unsigned r = c.i + 0x7FFFu + ((c.i >> 16) & 1u);
  return (u16)(r >> 16);
}
__device__ __forceinline__ unsigned cvt_pk(float lo, float hi) {
  unsigned r;
  asm("v_cvt_pk_bf16_f32 %0, %1, %2" : "=v"(r) : "v"(lo), "v"(hi));
  return r;
}
__device__ __forceinline__ void gl2lds16(const u16* g, u16* l) {
  __builtin_amdgcn_global_load_lds(
      (const __attribute__((address_space(1))) unsigned int*)(uintptr_t)g,
      (__attribute__((address_space(3))) unsigned int*)(uintptr_t)l,
      16, 0, 0);
}

// ---------------- K0: convert weights to bf16 ----------------
__global__ void k_prep(const float* __restrict__ wo, const float* __restrict__ wq,
                       const float* __restrict__ wk, const float* __restrict__ wv,
                       u16* __restrict__ WT, u16* __restrict__ WQKV) {
  int i = blockIdx.x * 256 + threadIdx.x;
  if (i < 9 * 128 * 128) {
    int c = i & 127;
    int o = (i >> 7) & 127;
    int tap = i >> 14;
    WT[i] = f2bf(wo[((o * 128 + c) * 3 + tap / 3) * 3 + tap % 3]);
  } else {
    int j = i - 9 * 128 * 128;
    if (j < 3 * 16384) {
      int sel = j >> 14, rest = j & 16383;
      const float* w = sel == 0 ? wq : (sel == 1 ? wk : wv);
      WQKV[j] = f2bf(w[rest]);
    }
  }
}

// ---------------- K1: fused QKV 1x1 conv + window scatter ----------------
// grid 1024: blk = b*512 + tw*32 + th. block 256 (4 waves).
// B-fragments (x) loaded DIRECTLY to registers; LDS = Ot only (34.8 KB).
// Q/K/V layout: [bh][s][d], d = pixw*32 + dph.
__global__ __launch_bounds__(256) void k_qkv(
    const float* __restrict__ x, const u16* __restrict__ WQKV,
    const float* __restrict__ bq, const float* __restrict__ bk,
    const float* __restrict__ bv,
    u16* __restrict__ Q, u16* __restrict__ K, u16* __restrict__ V) {
  const int blk = blockIdx.x;
  const int b = blk >> 9;
  const int t = blk & 511;
  const int th = t & 31, tw = t >> 5;
  const int h0 = th * 8, w0 = tw * 16;
  const int s0 = th * 32 + tw * 2;
  const int tid = threadIdx.x, lane = tid & 63, wid = tid >> 6;
  const int wr = wid >> 1, wc = wid & 1;
  const int g = lane >> 4, l15 = lane & 15;

  __shared__ u16 Ot[128 * 136];       // 34816 B — sole LDS

  bf16x8 bfrag[4][4];
  {
    const float* xb = x + (size_t)b * 8388608 + (size_t)(g * 8) * 65536
                        + (h0 + wc * 4) * 256 + w0 + l15;
    #pragma unroll
    for (int ks = 0; ks < 4; ++ks)
      #pragma unroll
      for (int e2 = 0; e2 < 4; ++e2) {
        const float* pa = xb + (size_t)(ks * 32 + e2 * 2) * 65536;
        const float* pb = pa + 65536;
        #pragma unroll
        for (int n = 0; n < 4; ++n)
          ((unsigned*)&bfrag[ks][n])[e2] = cvt_pk(pa[n * 256], pb[n * 256]);
      }
  }

  for (int sel = 0; sel < 3; ++sel) {
    const u16* w = WQKV + sel * 16384;
    const float* bias = sel == 0 ? bq : (sel == 1 ? bk : bv);
    u16* qkv = sel == 0 ? Q : (sel == 1 ? K : V);

    f32x4 acc[4][4] = {};
    #pragma unroll
    for (int ks = 0; ks < 4; ++ks) {
      bf16x8 a[4];
      #pragma unroll
      for (int m = 0; m < 4; ++m) {
        int o = wr * 64 + m * 16 + l15;
        a[m] = *(const bf16x8*)(w + o * 128 + ks * 32 + g * 8);
      }
      #pragma unroll
      for (int m = 0; m < 4; ++m)
        #pragma unroll
        for (int n = 0; n < 4; ++n)
          acc[m][n] = __builtin_amdgcn_mfma_f32_16x16x32_bf16(a[m], bfrag[ks][n], acc[m][n], 0, 0, 0);
    }

    float4 bias4[4];
    #pragma unroll
    for (int m = 0; m < 4; ++m)
      bias4[m] = *(const float4*)&bias[wr * 64 + m * 16 + g * 4];

    __syncthreads();
    #pragma unroll
    for (int m = 0; m < 4; ++m) {
      int o0 = wr * 64 + m * 16 + g * 4;
      #pragma unroll
      for (int n = 0; n < 4; ++n) {
        int p = wc * 64 + n * 16 + l15;
        unsigned r0 = cvt_pk(acc[m][n][0] + bias4[m].x, acc[m][n][1] + bias4[m].y);
        unsigned r1 = cvt_pk(acc[m][n][2] + bias4[m].z, acc[m][n][3] + bias4[m].w);
        unsigned* dp = (unsigned*)&Ot[p * 136 + o0];
        dp[0] = r0; dp[1] = r1;
      }
    }
    __syncthreads();
    #pragma unroll
    for (int it = 0; it < 8; ++it) {
      int head = it >> 1, s2 = it & 1;
      int pixw = tid >> 2;
      int dphc = tid & 3;
      int pl = (pixw >> 3) * 16 + s2 * 8 + (pixw & 7);
      bf16x8 vv = *(const bf16x8*)&Ot[pl * 136 + head * 32 + dphc * 8];
      size_t gaddr = ((size_t)((b * 4 + head) * 1024 + s0 + s2)) * 2048 + pixw * 32 + dphc * 8;
      *(bf16x8*)(qkv + gaddr) = vv;
    }
  }
}

// ---------------- K2: fused {ATT = bf16(Q K^T * scale)} + {VT transpose} ----------------
// grid 1536: wgid<512 -> qk (bh = wgid&7, tm fastest, dbuf staging, LDS-transposed
//            bf16 ATT stores); wgid>=512 -> vt (idx = wgid-512, bh = idx&7).
__global__ __launch_bounds__(256) void k_qkvt(const u16* __restrict__ Q,
                                              const u16* __restrict__ K,
                                              u16* __restrict__ ATT,
                                              const u16* __restrict__ V,
                                              u16* __restrict__ VT) {
  __shared__ __align__(16) u16 smem[17408];   // 32 KB dbuf / vt tile; 34.8 KB Ot alias
  const int tid = threadIdx.x, lane = tid & 63, wid = tid >> 6;

  if (blockIdx.x < 512) {
    const int bh = blockIdx.x & 7;
    const int tile = blockIdx.x >> 3;
    const int tm = tile & 7, tn = tile >> 3;
    const int row0 = tm * 128, col0 = tn * 128;
    const int wr = wid >> 1, wc = wid & 1;
    const u16* Ab = Q + (size_t)bh * 1024 * 2048 + (size_t)row0 * 2048;
    const u16* Bb = K + (size_t)bh * 1024 * 2048 + (size_t)col0 * 2048;
    f32x4 acc[4][4] = {};
    const int lr = lane >> 2, lc = lane & 3;
    const int scs = lc ^ ((lr >> 1) & 3);
    const int rsw = ((lane & 15) >> 1) & 3;

    auto stage = [&](int k0, int bf) {
      u16* As = smem + bf * 8192;
      u16* Bs = smem + 4096 + bf * 8192;
      const u16* s0 = Ab + (size_t)(wid * 16 + lr) * 2048 + k0 + scs * 8;
      gl2lds16(s0, &As[wid * 512]);
      gl2lds16(s0 + (size_t)64 * 2048, &As[2048 + wid * 512]);
      const u16* s1 = Bb + (size_t)(wid * 16 + lr) * 2048 + k0 + scs * 8;
      gl2lds16(s1, &Bs[wid * 512]);
      gl2lds16(s1 + (size_t)64 * 2048, &Bs[2048 + wid * 512]);
    };

    stage(0, 0);
    asm volatile("s_waitcnt vmcnt(0)" ::: "memory");
    __syncthreads();
    int cur = 0;
    for (int k0 = 0; k0 < 2048; k0 += 32) {
      if (k0 + 32 < 2048) stage(k0 + 32, cur ^ 1);
      const u16* As = smem + cur * 8192;
      const u16* Bs = smem + 4096 + cur * 8192;
      bf16x8 a[4], bb[4];
      const int g = lane >> 4;
      const int chp = (g ^ rsw) * 8;
      #pragma unroll
      for (int m = 0; m < 4; ++m)
        a[m] = *(const bf16x8*)&As[(wr * 64 + m * 16 + (lane & 15)) * 32 + chp];
      #pragma unroll
      for (int n = 0; n < 4; ++n)
        bb[n] = *(const bf16x8*)&Bs[(wc * 64 + n * 16 + (lane & 15)) * 32 + chp];
      #pragma unroll
      for (int m = 0; m < 4; ++m)
        #pragma unroll
        for (int n = 0; n < 4; ++n)
          acc[m][n] = __builtin_amdgcn_mfma_f32_16x16x32_bf16(a[m], bb[n], acc[m][n], 0, 0, 0);
      asm volatile("s_waitcnt vmcnt(0)" ::: "memory");
      __syncthreads();
      cur ^= 1;
    }
    const float scale = 0.02209708691207961f;  // 1/sqrt(2048)
    // epilogue: scaled bf16 acc -> Ot (pitch 136) -> coalesced 256B-run stores
    u16* Ot = smem;
    #pragma unroll
    for (int m = 0; m < 4; ++m) {
      int r0 = wr * 64 + m * 16 + ((lane >> 4) << 2);
      #pragma unroll
      for (int n = 0; n < 4; ++n) {
        int dv = wc * 64 + n * 16 + (lane & 15);
        #pragma unroll
        for (int j = 0; j < 4; ++j)
          Ot[(r0 + j) * 136 + dv] = f2bf(acc[m][n][j] * scale);
      }
    }
    __syncthreads();
    u16* outb = ATT + (size_t)bh * 1024 * 1024 + (size_t)row0 * 1024 + col0;
    #pragma unroll
    for (int it = 0; it < 8; ++it) {
      int ci = it * 256 + tid;          // 0..2047
      int sl = ci >> 4;                 // q-row local
      int ch = ci & 15;                 // 8-col chunk
      bf16x8 vv = *(const bf16x8*)&Ot[sl * 136 + ch * 8];
      *(bf16x8*)(outb + (size_t)sl * 1024 + ch * 8) = vv;
    }
  } else {
    const int idx = blockIdx.x - 512;
    const int bh = idx & 7;
    const int t2 = idx >> 3;
    const int ts = t2 & 7, td = t2 >> 3;
    const int s0 = ts * 128, d0 = td * 128;
    u16* T = smem;                 // [dv][s], s-chunk XOR-swizzled
    const u16* Vb = V + (size_t)bh * 1024 * 2048 + (size_t)s0 * 2048 + d0;

    #pragma unroll
    for (int pass = 0; pass < 8; ++pass) {
      int r = pass * 16 + (tid >> 4);
      int c8 = (tid & 15) * 8;
      union { uint4 u; u16 e[8]; } d;
      d.u = *(const uint4*)(Vb + (size_t)r * 2048 + c8);
      int chunk = (r >> 3) ^ ((c8 >> 3) & 15);
      #pragma unroll
      for (int e = 0; e < 8; ++e)
        T[(c8 + e) * 128 + chunk * 8 + (r & 7)] = d.e[e];
    }
    __syncthreads();
    u16* VTb = VT + (size_t)bh * 2048 * 1024 + (size_t)d0 * 1024 + s0;
    #pragma unroll
    for (int pass = 0; pass < 8; ++pass) {
      int rd = pass * 16 + (tid >> 4);
      int c8 = (tid & 15) * 8;
      int chunk = (c8 >> 3) ^ ((rd >> 3) & 15);
      bf16x8 v = *(const bf16x8*)&T[rd * 128 + chunk * 8];
      *(bf16x8*)(VTb + (size_t)rd * 1024 + c8) = v;
    }
  }
}

// ---------------- K3: row softmax (bf16 ATT in, bf16 P out) ----------------
__global__ __launch_bounds__(256) void k_softmax(const u16* __restrict__ ATT,
                                                 u16* __restrict__ P) {
  const int row = blockIdx.x;
  const u16* a = ATT + (size_t)row * 1024;
  const int tid = threadIdx.x;
  u16x4 raw = *(const u16x4*)(a + tid * 4);
  float v0 = bf2f(raw[0]), v1 = bf2f(raw[1]), v2 = bf2f(raw[2]), v3 = bf2f(raw[3]);
  float mx = fmaxf(fmaxf(v0, v1), fmaxf(v2, v3));
  #pragma unroll
  for (int off = 32; off; off >>= 1) mx = fmaxf(mx, __shfl_xor(mx, off, 64));
  __shared__ float red[8];
  if ((tid & 63) == 0) red[tid >> 6] = mx;
  __syncthreads();
  mx = fmaxf(fmaxf(red[0], red[1]), fmaxf(red[2], red[3]));
  float e0 = __expf(v0 - mx), e1 = __expf(v1 - mx);
  float e2 = __expf(v2 - mx), e3 = __expf(v3 - mx);
  float s = e0 + e1 + e2 + e3;
  #pragma unroll
  for (int off = 32; off; off >>= 1) s += __shfl_xor(s, off, 64);
  if ((tid & 63) == 0) red[4 + (tid >> 6)] = s;
  __syncthreads();
  s = red[4] + red[5] + red[6] + red[7];
  float inv = 1.0f / s;
  u16x4 o = { f2bf(e0 * inv), f2bf(e1 * inv), f2bf(e2 * inv), f2bf(e3 * inv) };
  *(u16x4*)(P + (size_t)row * 1024 + tid * 4) = o;
}

// ---------------- K4: Y = P V via VT, write NHWC ----------------
// grid 1024 1-D: bh = wgid&7; tm fastest. Double-buffered staging.
__global__ __launch_bounds__(256) void k_pv(const u16* __restrict__ P,
                                            const u16* __restrict__ VT,
                                            u16* __restrict__ Yn) {
  const int bh = blockIdx.x & 7;
  const int tile = blockIdx.x >> 3;
  const int tm = tile & 7, tn = tile >> 3;
  const int row0 = tm * 128, col0 = tn * 128;
  const int tid = threadIdx.x, lane = tid & 63, wid = tid >> 6;
  const int wr = wid >> 1, wc = wid & 1;
  __shared__ __align__(16) u16 smem[17408];   // dbuf 32KB; Ot 34.8KB aliased
  u16* Ot = smem;
  const u16* Pb = P + (size_t)bh * 1024 * 1024 + (size_t)row0 * 1024;
  const u16* VTb = VT + (size_t)bh * 2048 * 1024 + (size_t)col0 * 1024;
  f32x4 acc[4][4] = {};
  const int lr = lane >> 2, lc = lane & 3;
  const int scs = lc ^ ((lr >> 1) & 3);
  const int rsw = ((lane & 15) >> 1) & 3;

  auto stage = [&](int k0, int bf) {
    u16* As = smem + bf * 8192;
    u16* Bs = smem + 4096 + bf * 8192;
    const u16* s0 = Pb + (size_t)(wid * 16 + lr) * 1024 + k0 + scs * 8;
    gl2lds16(s0, &As[wid * 512]);
    gl2lds16(s0 + (size_t)64 * 1024, &As[2048 + wid * 512]);
    const u16* s1 = VTb + (size_t)(wid * 16 + lr) * 1024 + k0 + scs * 8;
    gl2lds16(s1, &Bs[wid * 512]);
    gl2lds16(s1 + (size_t)64 * 1024, &Bs[2048 + wid * 512]);
  };

  stage(0, 0);
  asm volatile("s_waitcnt vmcnt(0)" ::: "memory");
  __syncthreads();
  int cur = 0;
  for (int k0 = 0; k0 < 1024; k0 += 32) {
    if (k0 + 32 < 1024) stage(k0 + 32, cur ^ 1);
    const u16* As = smem + cur * 8192;
    const u16* Bs = smem + 4096 + cur * 8192;
    bf16x8 a[4], bb[4];
    const int g = lane >> 4;
    const int chp = (g ^ rsw) * 8;
    #pragma unroll
    for (int m = 0; m < 4; ++m)
      a[m] = *(const bf16x8*)&As[(wr * 64 + m * 16 + (lane & 15)) * 32 + chp];
    #pragma unroll
    for (int n = 0; n < 4; ++n)
      bb[n] = *(const bf16x8*)&Bs[(wc * 64 + n * 16 + (lane & 15)) * 32 + chp];
    #pragma unroll
    for (int m = 0; m < 4; ++m)
      #pragma unroll
      for (int n = 0; n < 4; ++n)
        acc[m][n] = __builtin_amdgcn_mfma_f32_16x16x32_bf16(a[m], bb[n], acc[m][n], 0, 0, 0);
    asm volatile("s_waitcnt vmcnt(0)" ::: "memory");
    __syncthreads();
    cur ^= 1;
  }

  #pragma unroll
  for (int m = 0; m < 4; ++m) {
    int r0 = wr * 64 + m * 16 + ((lane >> 4) << 2);
    #pragma unroll
    for (int n = 0; n < 4; ++n) {
      int dv = wc * 64 + n * 16 + (lane & 15);
      #pragma unroll
      for (int j = 0; j < 4; ++j)
        Ot[(r0 + j) * 136 + dv] = f2bf(acc[m][n][j]);
    }
  }
  __syncthreads();
  const int b = bh >> 2, head = bh & 3;
  const int pixw0 = tn * 4;
  #pragma unroll
  for (int it = 0; it < 8; ++it) {
    int ci = it * 256 + tid;
    int sl = ci >> 4;
    int pxl = (ci >> 2) & 3;
    int dc = ci & 3;
    bf16x8 vv = *(const bf16x8*)&Ot[sl * 136 + pxl * 32 + dc * 8];
    int s = row0 + sl, oh = s >> 5, ow = s & 31;
    int pixw = pixw0 + pxl, ph = pixw >> 3, pw = pixw & 7;
    int h = oh * 8 + ph, w2 = ow * 8 + pw;
    size_t gaddr = (((size_t)(b * 256 + h) * 256) + w2) * 128 + head * 32 + dc * 8;
    *(bf16x8*)(Yn + gaddr) = vv;
  }
}

// ---------------- K5: 3x3 reflect conv + bias + LeakyReLU (NHWC in, NCHW fp32 out) ----------------
__global__ __launch_bounds__(512, 2) void k_conv(const u16* __restrict__ Yn,
                                                 const u16* __restrict__ WT,
                                                 const float* __restrict__ bo,
                                                 float* __restrict__ out) {
  const int wgid = blockIdx.x;
  const int r7 = wgid & 7;
  const int b = (r7 >> 2) & 1;
  const int w0 = ((r7 >> 1) & 1) * 128;
  const int h0 = ((r7 & 1) * 32 + (wgid >> 3)) * 4;     // 0,4,...,252
  const int tid = threadIdx.x, lane = tid & 63, wid = tid >> 6;
  const int wo_ = wid & 1;
  const int wh = wid >> 1;
  const int g = lane >> 4, l15 = lane & 15;
  __shared__ u16 S[6][136 * 64];
  __shared__ u16 WTl[2][8192];
  f32x4 acc[4][8] = {};

  auto stageS = [&](int chalf) {
    for (int g5 = wid; g5 < 102; g5 += 8) {
      int rowi = g5 / 17, grp = g5 % 17;
      int rg = grp * 8 + (lane >> 3);
      int chunk = lane & 7;
      int row = h0 + rowi - 1;
      row = row < 0 ? 1 : (row > 255 ? 254 : row);
      int wsrc = w0 - 1 + rg;
      wsrc = wsrc < 0 ? 1 : (wsrc > 255 ? 254 : wsrc);
      const u16* src = Yn + ((size_t)(b * 256 + row) * 256 + wsrc) * 128 + chalf * 64
                         + ((chunk ^ (rg & 7)) * 8);
      gl2lds16(src, &S[rowi][grp * 512]);
    }
  };
  auto stageWT = [&](int chalf, int tap, int nb) {
    #pragma unroll
    for (int r2 = 0; r2 < 2; ++r2) {
      int g5 = wid + r2 * 8;
      int orow = g5 * 8 + (lane >> 3);
      int csrc = (lane & 7) ^ (lane >> 3);
      const u16* src = WT + ((size_t)tap * 128 + orow) * 128 + chalf * 64 + csrc * 8;
      gl2lds16(src, &WTl[nb][g5 * 512]);
    }
  };

  int buf = 0;
  stageS(0);
  stageWT(0, 0, 0);
  asm volatile("s_waitcnt vmcnt(0)" ::: "memory");
  __syncthreads();

  #pragma unroll
  for (int chalf = 0; chalf < 2; ++chalf) {
    if (chalf) {
      __syncthreads();
      stageS(1);
      stageWT(1, 0, buf ^ 1);
      asm volatile("s_waitcnt vmcnt(0)" ::: "memory");
      __syncthreads();
      buf ^= 1;
    }
    #pragma unroll
    for (int ky = 0; ky < 3; ++ky) {
      #pragma unroll
      for (int kx = 0; kx < 3; ++kx) {
        const int tap = ky * 3 + kx;
        const bool hasNext = (tap < 8);
        if (hasNext) stageWT(chalf, tap + 1, buf ^ 1);
        bf16x8 areg[2][4];
        #pragma unroll
        for (int ckh = 0; ckh < 2; ++ckh)
          #pragma unroll
          for (int m = 0; m < 4; ++m) {
            int o = wo_ * 64 + m * 16 + l15;
            int cc2 = ((ckh << 2) + g) ^ (o & 7);
            areg[ckh][m] = *(const bf16x8*)&WTl[buf][o * 64 + cc2 * 8];
          }
        #pragma unroll
        for (int ckh = 0; ckh < 2; ++ckh) {
          #pragma unroll
          for (int nh = 0; nh < 2; ++nh) {
            bf16x8 bb[4];
            #pragma unroll
            for (int n4 = 0; n4 < 4; ++n4) {
              int p = (nh * 4 + n4) * 16 + l15 + kx;
              int chunk = ((ckh << 2) + g) ^ (p & 7);
              bb[n4] = *(const bf16x8*)&S[wh + ky][p * 64 + chunk * 8];
            }
            #pragma unroll
            for (int m = 0; m < 4; ++m)
              #pragma unroll
              for (int n4 = 0; n4 < 4; ++n4)
                acc[m][nh * 4 + n4] = __builtin_amdgcn_mfma_f32_16x16x32_bf16(
                    areg[ckh][m], bb[n4], acc[m][nh * 4 + n4], 0, 0, 0);
          }
        }
        if (hasNext) {
          asm volatile("s_waitcnt vmcnt(0)" ::: "memory");
          __syncthreads();
          buf ^= 1;
        }
      }
    }
  }
  #pragma unroll
  for (int m = 0; m < 4; ++m) {
    int o0 = wo_ * 64 + m * 16 + (g << 2);
    #pragma unroll
    for (int n = 0; n < 8; ++n) {
      int p = n * 16 + l15;
      #pragma unroll
      for (int j = 0; j < 4; ++j) {
        int o = o0 + j;
        float v = acc[m][n][j] + bo[o];
        v = v > 0.f ? v : 0.2f * v;
        out[(((size_t)b * 128 + o) << 16) + ((h0 + wh) << 8) + w0 + p] = v;
      }
    }
  }
}

extern "C" void kernel_launch(void* const* d_in, const int* in_sizes, int n_in,
                              void* d_out, int out_size, void* d_ws, size_t ws_size,
                              hipStream_t stream) {
  const float* x  = (const float*)d_in[0];
  // d_in[1] = mask: dead code in reference
  const float* wq = (const float*)d_in[2];
  const float* bq = (const float*)d_in[3];
  const float* wk = (const float*)d_in[4];
  const float* bk = (const float*)d_in[5];
  const float* wv = (const float*)d_in[6];
  const float* bv = (const float*)d_in[7];
  const float* wo = (const float*)d_in[8];
  const float* bo = (const float*)d_in[9];

  char* ws = (char*)d_ws;
  u16*   WT   = (u16*)(ws);                                 // 288 KiB
  u16*   WQKV = (u16*)(ws + (size_t)(512 << 10));           // 96 KiB
  u16*   Q   = (u16*)(ws + (size_t)(1  << 20));             // 32 MiB
  u16*   K   = (u16*)(ws + (size_t)(33 << 20));             // 32 MiB
  u16*   V   = (u16*)(ws + (size_t)(65 << 20));             // 32 MiB
  u16*   ATT = (u16*)(ws + (size_t)(97 << 20));             // 16 MiB bf16
  u16*   P   = (u16*)(ws + (size_t)(129 << 20));            // 16 MiB
  u16*   Yn  = (u16*)(ws + (size_t)(145 << 20));            // 32 MiB NHWC
  u16*   VT  = (u16*)(ws + (size_t)(177 << 20));            // 32 MiB [bh][d][s]
  float* outp = (float*)d_out;

  k_prep<<<768, 256, 0, stream>>>(wo, wq, wk, wv, WT, WQKV);
  k_qkv<<<1024, 256, 0, stream>>>(x, WQKV, bq, bk, bv, Q, K, V);
  k_qkvt<<<1536, 256, 0, stream>>>(Q, K, ATT, V, VT);
  k_softmax<<<8192, 256, 0, stream>>>(ATT, P);
  k_pv<<<1024, 256, 0, stream>>>(P, VT, Yn);
  k_conv<<<256, 512, 0, stream>>>(Yn, WT, bo, outp);
}

// Round 19
// 201.085 us; speedup vs baseline: 1.1142x; 1.0441x over previous
//
#include <hip/hip_runtime.h>
#include <hip/hip_bf16.h>
#include <stdint.h>

typedef unsigned short u16;
typedef __attribute__((ext_vector_type(8))) short bf16x8;
typedef __attribute__((ext_vector_type(4))) short bf16x4;
typedef __attribute__((ext_vector_type(4))) float f32x4;
typedef __attribute__((ext_vector_type(4))) unsigned short u16x4;

__device__ __forceinline__ float bf2f(u16 u) {
  union { unsigned i; float f; } c; c.i = ((unsigned)u) << 16; return c.f;
}
__device__ __forceinline__ u16 f2bf(float f) {
  union { float f; unsigned i; } c; c.f = f;
  unsigned r = c.i + 0x7FFFu + ((c.i >> 16) & 1u);
  return (u16)(r >> 16);
}
__device__ __forceinline__ unsigned cvt_pk(float lo, float hi) {
  unsigned r;
  asm("v_cvt_pk_bf16_f32 %0, %1, %2" : "=v"(r) : "v"(lo), "v"(hi));
  return r;
}
__device__ __forceinline__ void gl2lds16(const u16* g, u16* l) {
  __builtin_amdgcn_global_load_lds(
      (const __attribute__((address_space(1))) unsigned int*)(uintptr_t)g,
      (__attribute__((address_space(3))) unsigned int*)(uintptr_t)l,
      16, 0, 0);
}

// ---------------- K0: convert weights to bf16; zero RS ----------------
__global__ void k_prep(const float* __restrict__ wo, const float* __restrict__ wq,
                       const float* __restrict__ wk, const float* __restrict__ wv,
                       u16* __restrict__ WT, u16* __restrict__ WQKV,
                       float* __restrict__ RS) {
  int i = blockIdx.x * 256 + threadIdx.x;    // grid 800 -> 204800 = 147456+49152+8192
  if (i < 9 * 128 * 128) {
    int c = i & 127;
    int o = (i >> 7) & 127;
    int tap = i >> 14;
    WT[i] = f2bf(wo[((o * 128 + c) * 3 + tap / 3) * 3 + tap % 3]);
  } else if (i < 9 * 128 * 128 + 3 * 16384) {
    int j = i - 9 * 128 * 128;
    int sel = j >> 14, rest = j & 16383;
    const float* w = sel == 0 ? wq : (sel == 1 ? wk : wv);
    WQKV[j] = f2bf(w[rest]);
  } else {
    int rsi = i - (9 * 128 * 128 + 3 * 16384);
    if (rsi < 8192) RS[rsi] = 0.f;
  }
}

// ---------------- K1: fused QKV 1x1 conv + window scatter ----------------
// grid 1024: blk = b*512 + tw*32 + th. block 256 (4 waves).
// B-fragments (x) loaded DIRECTLY to registers; LDS = Ot only (34.8 KB).
// Q/K/V layout: [bh][s][d], d = pixw*32 + dph.
__global__ __launch_bounds__(256) void k_qkv(
    const float* __restrict__ x, const u16* __restrict__ WQKV,
    const float* __restrict__ bq, const float* __restrict__ bk,
    const float* __restrict__ bv,
    u16* __restrict__ Q, u16* __restrict__ K, u16* __restrict__ V) {
  const int blk = blockIdx.x;
  const int b = blk >> 9;
  const int t = blk & 511;
  const int th = t & 31, tw = t >> 5;
  const int h0 = th * 8, w0 = tw * 16;
  const int s0 = th * 32 + tw * 2;
  const int tid = threadIdx.x, lane = tid & 63, wid = tid >> 6;
  const int wr = wid >> 1, wc = wid & 1;
  const int g = lane >> 4, l15 = lane & 15;

  __shared__ u16 Ot[128 * 136];       // 34816 B — sole LDS

  bf16x8 bfrag[4][4];
  {
    const float* xb = x + (size_t)b * 8388608 + (size_t)(g * 8) * 65536
                        + (h0 + wc * 4) * 256 + w0 + l15;
    #pragma unroll
    for (int ks = 0; ks < 4; ++ks)
      #pragma unroll
      for (int e2 = 0; e2 < 4; ++e2) {
        const float* pa = xb + (size_t)(ks * 32 + e2 * 2) * 65536;
        const float* pb = pa + 65536;
        #pragma unroll
        for (int n = 0; n < 4; ++n)
          ((unsigned*)&bfrag[ks][n])[e2] = cvt_pk(pa[n * 256], pb[n * 256]);
      }
  }

  for (int sel = 0; sel < 3; ++sel) {
    const u16* w = WQKV + sel * 16384;
    const float* bias = sel == 0 ? bq : (sel == 1 ? bk : bv);
    u16* qkv = sel == 0 ? Q : (sel == 1 ? K : V);

    f32x4 acc[4][4] = {};
    #pragma unroll
    for (int ks = 0; ks < 4; ++ks) {
      bf16x8 a[4];
      #pragma unroll
      for (int m = 0; m < 4; ++m) {
        int o = wr * 64 + m * 16 + l15;
        a[m] = *(const bf16x8*)(w + o * 128 + ks * 32 + g * 8);
      }
      #pragma unroll
      for (int m = 0; m < 4; ++m)
        #pragma unroll
        for (int n = 0; n < 4; ++n)
          acc[m][n] = __builtin_amdgcn_mfma_f32_16x16x32_bf16(a[m], bfrag[ks][n], acc[m][n], 0, 0, 0);
    }

    float4 bias4[4];
    #pragma unroll
    for (int m = 0; m < 4; ++m)
      bias4[m] = *(const float4*)&bias[wr * 64 + m * 16 + g * 4];

    __syncthreads();
    #pragma unroll
    for (int m = 0; m < 4; ++m) {
      int o0 = wr * 64 + m * 16 + g * 4;
      #pragma unroll
      for (int n = 0; n < 4; ++n) {
        int p = wc * 64 + n * 16 + l15;
        unsigned r0 = cvt_pk(acc[m][n][0] + bias4[m].x, acc[m][n][1] + bias4[m].y);
        unsigned r1 = cvt_pk(acc[m][n][2] + bias4[m].z, acc[m][n][3] + bias4[m].w);
        unsigned* dp = (unsigned*)&Ot[p * 136 + o0];
        dp[0] = r0; dp[1] = r1;
      }
    }
    __syncthreads();
    #pragma unroll
    for (int it = 0; it < 8; ++it) {
      int head = it >> 1, s2 = it & 1;
      int pixw = tid >> 2;
      int dphc = tid & 3;
      int pl = (pixw >> 3) * 16 + s2 * 8 + (pixw & 7);
      bf16x8 vv = *(const bf16x8*)&Ot[pl * 136 + head * 32 + dphc * 8];
      size_t gaddr = ((size_t)((b * 4 + head) * 1024 + s0 + s2)) * 2048 + pixw * 32 + dphc * 8;
      *(bf16x8*)(qkv + gaddr) = vv;
    }
  }
}

// ---------------- K2: fused {EATT = exp(Q K^T * scale), row-sums} + {VT transpose} ----------------
// grid 1536: wgid<512 -> qk (bh = wgid&7, tm fastest, dbuf staging); wgid>=512 -> vt.
// EATT holds UNNORMALIZED exp in bf16; RS[bh*1024+r] accumulates row sums (atomicAdd).
__global__ __launch_bounds__(256) void k_qkvt(const u16* __restrict__ Q,
                                              const u16* __restrict__ K,
                                              u16* __restrict__ EATT,
                                              const u16* __restrict__ V,
                                              u16* __restrict__ VT,
                                              float* __restrict__ RS) {
  __shared__ __align__(16) u16 smem[17408];   // 32 KB dbuf / vt tile; 34.8 KB Ot alias
  const int tid = threadIdx.x, lane = tid & 63, wid = tid >> 6;

  if (blockIdx.x < 512) {
    const int bh = blockIdx.x & 7;
    const int tile = blockIdx.x >> 3;
    const int tm = tile & 7, tn = tile >> 3;
    const int row0 = tm * 128, col0 = tn * 128;
    const int wr = wid >> 1, wc = wid & 1;
    const u16* Ab = Q + (size_t)bh * 1024 * 2048 + (size_t)row0 * 2048;
    const u16* Bb = K + (size_t)bh * 1024 * 2048 + (size_t)col0 * 2048;
    f32x4 acc[4][4] = {};
    const int lr = lane >> 2, lc = lane & 3;
    const int scs = lc ^ ((lr >> 1) & 3);
    const int rsw = ((lane & 15) >> 1) & 3;

    auto stage = [&](int k0, int bf) {
      u16* As = smem + bf * 8192;
      u16* Bs = smem + 4096 + bf * 8192;
      const u16* s0 = Ab + (size_t)(wid * 16 + lr) * 2048 + k0 + scs * 8;
      gl2lds16(s0, &As[wid * 512]);
      gl2lds16(s0 + (size_t)64 * 2048, &As[2048 + wid * 512]);
      const u16* s1 = Bb + (size_t)(wid * 16 + lr) * 2048 + k0 + scs * 8;
      gl2lds16(s1, &Bs[wid * 512]);
      gl2lds16(s1 + (size_t)64 * 2048, &Bs[2048 + wid * 512]);
    };

    stage(0, 0);
    asm volatile("s_waitcnt vmcnt(0)" ::: "memory");
    __syncthreads();
    int cur = 0;
    for (int k0 = 0; k0 < 2048; k0 += 32) {
      if (k0 + 32 < 2048) stage(k0 + 32, cur ^ 1);
      const u16* As = smem + cur * 8192;
      const u16* Bs = smem + 4096 + cur * 8192;
      bf16x8 a[4], bb[4];
      const int g = lane >> 4;
      const int chp = (g ^ rsw) * 8;
      #pragma unroll
      for (int m = 0; m < 4; ++m)
        a[m] = *(const bf16x8*)&As[(wr * 64 + m * 16 + (lane & 15)) * 32 + chp];
      #pragma unroll
      for (int n = 0; n < 4; ++n)
        bb[n] = *(const bf16x8*)&Bs[(wc * 64 + n * 16 + (lane & 15)) * 32 + chp];
      #pragma unroll
      for (int m = 0; m < 4; ++m)
        #pragma unroll
        for (int n = 0; n < 4; ++n)
          acc[m][n] = __builtin_amdgcn_mfma_f32_16x16x32_bf16(a[m], bb[n], acc[m][n], 0, 0, 0);
      asm volatile("s_waitcnt vmcnt(0)" ::: "memory");
      __syncthreads();
      cur ^= 1;
    }
    const float scale = 0.02209708691207961f;  // 1/sqrt(2048)
    // epilogue: e = exp(att) -> Ot bf16; row-sum partials -> RS atomicAdd
    u16* Ot = smem;
    float psum[4][4];
    #pragma unroll
    for (int m = 0; m < 4; ++m) {
      int r0 = wr * 64 + m * 16 + ((lane >> 4) << 2);
      #pragma unroll
      for (int j = 0; j < 4; ++j) psum[m][j] = 0.f;
      #pragma unroll
      for (int n = 0; n < 4; ++n) {
        int dv = wc * 64 + n * 16 + (lane & 15);
        #pragma unroll
        for (int j = 0; j < 4; ++j) {
          float e = __expf(acc[m][n][j] * scale);
          Ot[(r0 + j) * 136 + dv] = f2bf(e);
          psum[m][j] += e;
        }
      }
    }
    #pragma unroll
    for (int m = 0; m < 4; ++m)
      #pragma unroll
      for (int j = 0; j < 4; ++j) {
        float v = psum[m][j];
        v += __shfl_xor(v, 1, 64);
        v += __shfl_xor(v, 2, 64);
        v += __shfl_xor(v, 4, 64);
        v += __shfl_xor(v, 8, 64);
        if ((lane & 15) == 0) {
          int r = row0 + wr * 64 + m * 16 + ((lane >> 4) << 2) + j;
          atomicAdd(&RS[bh * 1024 + r], v);
        }
      }
    __syncthreads();
    u16* outb = EATT + (size_t)bh * 1024 * 1024 + (size_t)row0 * 1024 + col0;
    #pragma unroll
    for (int it = 0; it < 8; ++it) {
      int ci = it * 256 + tid;          // 0..2047
      int sl = ci >> 4;                 // q-row local
      int ch = ci & 15;                 // 8-col chunk
      bf16x8 vv = *(const bf16x8*)&Ot[sl * 136 + ch * 8];
      *(bf16x8*)(outb + (size_t)sl * 1024 + ch * 8) = vv;
    }
  } else {
    const int idx = blockIdx.x - 512;
    const int bh = idx & 7;
    const int t2 = idx >> 3;
    const int ts = t2 & 7, td = t2 >> 3;
    const int s0 = ts * 128, d0 = td * 128;
    u16* T = smem;                 // [dv][s], s-chunk XOR-swizzled
    const u16* Vb = V + (size_t)bh * 1024 * 2048 + (size_t)s0 * 2048 + d0;

    #pragma unroll
    for (int pass = 0; pass < 8; ++pass) {
      int r = pass * 16 + (tid >> 4);
      int c8 = (tid & 15) * 8;
      union { uint4 u; u16 e[8]; } d;
      d.u = *(const uint4*)(Vb + (size_t)r * 2048 + c8);
      int chunk = (r >> 3) ^ ((c8 >> 3) & 15);
      #pragma unroll
      for (int e = 0; e < 8; ++e)
        T[(c8 + e) * 128 + chunk * 8 + (r & 7)] = d.e[e];
    }
    __syncthreads();
    u16* VTb = VT + (size_t)bh * 2048 * 1024 + (size_t)d0 * 1024 + s0;
    #pragma unroll
    for (int pass = 0; pass < 8; ++pass) {
      int rd = pass * 16 + (tid >> 4);
      int c8 = (tid & 15) * 8;
      int chunk = (c8 >> 3) ^ ((rd >> 3) & 15);
      bf16x8 v = *(const bf16x8*)&T[rd * 128 + chunk * 8];
      *(bf16x8*)(VTb + (size_t)rd * 1024 + c8) = v;
    }
  }
}

// ---------------- K4: Y = (EATT V) / RS via VT, write NHWC ----------------
// grid 1024 1-D: bh = wgid&7; tm fastest. Double-buffered staging.
// A-operand = unnormalized exp (bf16); normalization applied per-row in epilogue.
__global__ __launch_bounds__(256) void k_pv(const u16* __restrict__ EATT,
                                            const u16* __restrict__ VT,
                                            const float* __restrict__ RS,
                                            u16* __restrict__ Yn) {
  const int bh = blockIdx.x & 7;
  const int tile = blockIdx.x >> 3;
  const int tm = tile & 7, tn = tile >> 3;
  const int row0 = tm * 128, col0 = tn * 128;
  const int tid = threadIdx.x, lane = tid & 63, wid = tid >> 6;
  const int wr = wid >> 1, wc = wid & 1;
  __shared__ __align__(16) u16 smem[17408];   // dbuf 32KB; Ot 34.8KB aliased
  u16* Ot = smem;
  const u16* Pb = EATT + (size_t)bh * 1024 * 1024 + (size_t)row0 * 1024;
  const u16* VTb = VT + (size_t)bh * 2048 * 1024 + (size_t)col0 * 1024;
  f32x4 acc[4][4] = {};
  const int lr = lane >> 2, lc = lane & 3;
  const int scs = lc ^ ((lr >> 1) & 3);
  const int rsw = ((lane & 15) >> 1) & 3;

  auto stage = [&](int k0, int bf) {
    u16* As = smem + bf * 8192;
    u16* Bs = smem + 4096 + bf * 8192;
    const u16* s0 = Pb + (size_t)(wid * 16 + lr) * 1024 + k0 + scs * 8;
    gl2lds16(s0, &As[wid * 512]);
    gl2lds16(s0 + (size_t)64 * 1024, &As[2048 + wid * 512]);
    const u16* s1 = VTb + (size_t)(wid * 16 + lr) * 1024 + k0 + scs * 8;
    gl2lds16(s1, &Bs[wid * 512]);
    gl2lds16(s1 + (size_t)64 * 1024, &Bs[2048 + wid * 512]);
  };

  stage(0, 0);
  asm volatile("s_waitcnt vmcnt(0)" ::: "memory");
  __syncthreads();
  int cur = 0;
  for (int k0 = 0; k0 < 1024; k0 += 32) {
    if (k0 + 32 < 1024) stage(k0 + 32, cur ^ 1);
    const u16* As = smem + cur * 8192;
    const u16* Bs = smem + 4096 + cur * 8192;
    bf16x8 a[4], bb[4];
    const int g = lane >> 4;
    const int chp = (g ^ rsw) * 8;
    #pragma unroll
    for (int m = 0; m < 4; ++m)
      a[m] = *(const bf16x8*)&As[(wr * 64 + m * 16 + (lane & 15)) * 32 + chp];
    #pragma unroll
    for (int n = 0; n < 4; ++n)
      bb[n] = *(const bf16x8*)&Bs[(wc * 64 + n * 16 + (lane & 15)) * 32 + chp];
    #pragma unroll
    for (int m = 0; m < 4; ++m)
      #pragma unroll
      for (int n = 0; n < 4; ++n)
        acc[m][n] = __builtin_amdgcn_mfma_f32_16x16x32_bf16(a[m], bb[n], acc[m][n], 0, 0, 0);
    asm volatile("s_waitcnt vmcnt(0)" ::: "memory");
    __syncthreads();
    cur ^= 1;
  }

  #pragma unroll
  for (int m = 0; m < 4; ++m) {
    int r0 = wr * 64 + m * 16 + ((lane >> 4) << 2);
    float inv[4];
    #pragma unroll
    for (int j = 0; j < 4; ++j)
      inv[j] = 1.0f / RS[bh * 1024 + row0 + r0 + j];
    #pragma unroll
    for (int n = 0; n < 4; ++n) {
      int dv = wc * 64 + n * 16 + (lane & 15);
      #pragma unroll
      for (int j = 0; j < 4; ++j)
        Ot[(r0 + j) * 136 + dv] = f2bf(acc[m][n][j] * inv[j]);
    }
  }
  __syncthreads();
  const int b = bh >> 2, head = bh & 3;
  const int pixw0 = tn * 4;
  #pragma unroll
  for (int it = 0; it < 8; ++it) {
    int ci = it * 256 + tid;
    int sl = ci >> 4;
    int pxl = (ci >> 2) & 3;
    int dc = ci & 3;
    bf16x8 vv = *(const bf16x8*)&Ot[sl * 136 + pxl * 32 + dc * 8];
    int s = row0 + sl, oh = s >> 5, ow = s & 31;
    int pixw = pixw0 + pxl, ph = pixw >> 3, pw = pixw & 7;
    int h = oh * 8 + ph, w2 = ow * 8 + pw;
    size_t gaddr = (((size_t)(b * 256 + h) * 256) + w2) * 128 + head * 32 + dc * 8;
    *(bf16x8*)(Yn + gaddr) = vv;
  }
}

// ---------------- K5: 3x3 reflect conv + bias + LeakyReLU (NHWC in, NCHW fp32 out) ----------------
__global__ __launch_bounds__(512, 2) void k_conv(const u16* __restrict__ Yn,
                                                 const u16* __restrict__ WT,
                                                 const float* __restrict__ bo,
                                                 float* __restrict__ out) {
  const int wgid = blockIdx.x;
  const int r7 = wgid & 7;
  const int b = (r7 >> 2) & 1;
  const int w0 = ((r7 >> 1) & 1) * 128;
  const int h0 = ((r7 & 1) * 32 + (wgid >> 3)) * 4;     // 0,4,...,252
  const int tid = threadIdx.x, lane = tid & 63, wid = tid >> 6;
  const int wo_ = wid & 1;
  const int wh = wid >> 1;
  const int g = lane >> 4, l15 = lane & 15;
  __shared__ u16 S[6][136 * 64];
  __shared__ u16 WTl[2][8192];
  f32x4 acc[4][8] = {};

  auto stageS = [&](int chalf) {
    for (int g5 = wid; g5 < 102; g5 += 8) {
      int rowi = g5 / 17, grp = g5 % 17;
      int rg = grp * 8 + (lane >> 3);
      int chunk = lane & 7;
      int row = h0 + rowi - 1;
      row = row < 0 ? 1 : (row > 255 ? 254 : row);
      int wsrc = w0 - 1 + rg;
      wsrc = wsrc < 0 ? 1 : (wsrc > 255 ? 254 : wsrc);
      const u16* src = Yn + ((size_t)(b * 256 + row) * 256 + wsrc) * 128 + chalf * 64
                         + ((chunk ^ (rg & 7)) * 8);
      gl2lds16(src, &S[rowi][grp * 512]);
    }
  };
  auto stageWT = [&](int chalf, int tap, int nb) {
    #pragma unroll
    for (int r2 = 0; r2 < 2; ++r2) {
      int g5 = wid + r2 * 8;
      int orow = g5 * 8 + (lane >> 3);
      int csrc = (lane & 7) ^ (lane >> 3);
      const u16* src = WT + ((size_t)tap * 128 + orow) * 128 + chalf * 64 + csrc * 8;
      gl2lds16(src, &WTl[nb][g5 * 512]);
    }
  };

  int buf = 0;
  stageS(0);
  stageWT(0, 0, 0);
  asm volatile("s_waitcnt vmcnt(0)" ::: "memory");
  __syncthreads();

  #pragma unroll
  for (int chalf = 0; chalf < 2; ++chalf) {
    if (chalf) {
      __syncthreads();
      stageS(1);
      stageWT(1, 0, buf ^ 1);
      asm volatile("s_waitcnt vmcnt(0)" ::: "memory");
      __syncthreads();
      buf ^= 1;
    }
    #pragma unroll
    for (int ky = 0; ky < 3; ++ky) {
      #pragma unroll
      for (int kx = 0; kx < 3; ++kx) {
        const int tap = ky * 3 + kx;
        const bool hasNext = (tap < 8);
        if (hasNext) stageWT(chalf, tap + 1, buf ^ 1);
        bf16x8 areg[2][4];
        #pragma unroll
        for (int ckh = 0; ckh < 2; ++ckh)
          #pragma unroll
          for (int m = 0; m < 4; ++m) {
            int o = wo_ * 64 + m * 16 + l15;
            int cc2 = ((ckh << 2) + g) ^ (o & 7);
            areg[ckh][m] = *(const bf16x8*)&WTl[buf][o * 64 + cc2 * 8];
          }
        #pragma unroll
        for (int ckh = 0; ckh < 2; ++ckh) {
          #pragma unroll
          for (int nh = 0; nh < 2; ++nh) {
            bf16x8 bb[4];
            #pragma unroll
            for (int n4 = 0; n4 < 4; ++n4) {
              int p = (nh * 4 + n4) * 16 + l15 + kx;
              int chunk = ((ckh << 2) + g) ^ (p & 7);
              bb[n4] = *(const bf16x8*)&S[wh + ky][p * 64 + chunk * 8];
            }
            #pragma unroll
            for (int m = 0; m < 4; ++m)
              #pragma unroll
              for (int n4 = 0; n4 < 4; ++n4)
                acc[m][nh * 4 + n4] = __builtin_amdgcn_mfma_f32_16x16x32_bf16(
                    areg[ckh][m], bb[n4], acc[m][nh * 4 + n4], 0, 0, 0);
          }
        }
        if (hasNext) {
          asm volatile("s_waitcnt vmcnt(0)" ::: "memory");
          __syncthreads();
          buf ^= 1;
        }
      }
    }
  }
  #pragma unroll
  for (int m = 0; m < 4; ++m) {
    int o0 = wo_ * 64 + m * 16 + (g << 2);
    #pragma unroll
    for (int n = 0; n < 8; ++n) {
      int p = n * 16 + l15;
      #pragma unroll
      for (int j = 0; j < 4; ++j) {
        int o = o0 + j;
        float v = acc[m][n][j] + bo[o];
        v = v > 0.f ? v : 0.2f * v;
        out[(((size_t)b * 128 + o) << 16) + ((h0 + wh) << 8) + w0 + p] = v;
      }
    }
  }
}

extern "C" void kernel_launch(void* const* d_in, const int* in_sizes, int n_in,
                              void* d_out, int out_size, void* d_ws, size_t ws_size,
                              hipStream_t stream) {
  const float* x  = (const float*)d_in[0];
  // d_in[1] = mask: dead code in reference
  const float* wq = (const float*)d_in[2];
  const float* bq = (const float*)d_in[3];
  const float* wk = (const float*)d_in[4];
  const float* bk = (const float*)d_in[5];
  const float* wv = (const float*)d_in[6];
  const float* bv = (const float*)d_in[7];
  const float* wo = (const float*)d_in[8];
  const float* bo = (const float*)d_in[9];

  char* ws = (char*)d_ws;
  u16*   WT   = (u16*)(ws);                                 // 288 KiB
  u16*   WQKV = (u16*)(ws + (size_t)(512 << 10));           // 96 KiB
  u16*   Q   = (u16*)(ws + (size_t)(1  << 20));             // 32 MiB
  u16*   K   = (u16*)(ws + (size_t)(33 << 20));             // 32 MiB
  u16*   V   = (u16*)(ws + (size_t)(65 << 20));             // 32 MiB
  u16*   EATT= (u16*)(ws + (size_t)(97 << 20));             // 16 MiB bf16 exp
  float* RS  = (float*)(ws + (size_t)(129 << 20));          // 32 KiB row sums
  u16*   Yn  = (u16*)(ws + (size_t)(145 << 20));            // 32 MiB NHWC
  u16*   VT  = (u16*)(ws + (size_t)(177 << 20));            // 32 MiB [bh][d][s]
  float* outp = (float*)d_out;

  k_prep<<<800, 256, 0, stream>>>(wo, wq, wk, wv, WT, WQKV, RS);
  k_qkv<<<1024, 256, 0, stream>>>(x, WQKV, bq, bk, bv, Q, K, V);
  k_qkvt<<<1536, 256, 0, stream>>>(Q, K, EATT, V, VT, RS);
  k_pv<<<1024, 256, 0, stream>>>(EATT, VT, RS, Yn);
  k_conv<<<256, 512, 0, stream>>>(Yn, WT, bo, outp);
}

// Round 20
// 198.925 us; speedup vs baseline: 1.1263x; 1.0109x over previous
//
#include <hip/hip_runtime.h>
#include <hip/hip_bf16.h>
#include <stdint.h>

typedef unsigned short u16;
typedef __attribute__((ext_vector_type(8))) short bf16x8;
typedef __attribute__((ext_vector_type(4))) short bf16x4;
typedef __attribute__((ext_vector_type(4))) float f32x4;
typedef __attribute__((ext_vector_type(4))) unsigned short u16x4;

__device__ __forceinline__ float bf2f(u16 u) {
  union { unsigned i; float f; } c; c.i = ((unsigned)u) << 16; return c.f;
}
__device__ __forceinline__ u16 f2bf(float f) {
  union { float f; unsigned i; } c; c.f = f;
  unsigned r = c.i + 0x7FFFu + ((c.i >> 16) & 1u);
  return (u16)(r >> 16);
}
__device__ __forceinline__ unsigned cvt_pk(float lo, float hi) {
  unsigned r;
  asm("v_cvt_pk_bf16_f32 %0, %1, %2" : "=v"(r) : "v"(lo), "v"(hi));
  return r;
}
__device__ __forceinline__ void gl2lds16(const u16* g, u16* l) {
  __builtin_amdgcn_global_load_lds(
      (const __attribute__((address_space(1))) unsigned int*)(uintptr_t)g,
      (__attribute__((address_space(3))) unsigned int*)(uintptr_t)l,
      16, 0, 0);
}

// ---------------- K0: convert weights to bf16; zero RS ----------------
__global__ void k_prep(const float* __restrict__ wo, const float* __restrict__ wq,
                       const float* __restrict__ wk, const float* __restrict__ wv,
                       u16* __restrict__ WT, u16* __restrict__ WQKV,
                       float* __restrict__ RS) {
  int i = blockIdx.x * 256 + threadIdx.x;    // grid 800
  if (i < 9 * 128 * 128) {
    int c = i & 127;
    int o = (i >> 7) & 127;
    int tap = i >> 14;
    WT[i] = f2bf(wo[((o * 128 + c) * 3 + tap / 3) * 3 + tap % 3]);
  } else if (i < 9 * 128 * 128 + 3 * 16384) {
    int j = i - 9 * 128 * 128;
    int sel = j >> 14, rest = j & 16383;
    const float* w = sel == 0 ? wq : (sel == 1 ? wk : wv);
    WQKV[j] = f2bf(w[rest]);
  } else {
    int rsi = i - (9 * 128 * 128 + 3 * 16384);
    if (rsi < 8192) RS[rsi] = 0.f;
  }
}

// ---------------- K1: fused QKV 1x1 conv + window scatter ----------------
__global__ __launch_bounds__(256) void k_qkv(
    const float* __restrict__ x, const u16* __restrict__ WQKV,
    const float* __restrict__ bq, const float* __restrict__ bk,
    const float* __restrict__ bv,
    u16* __restrict__ Q, u16* __restrict__ K, u16* __restrict__ V) {
  const int blk = blockIdx.x;
  const int b = blk >> 9;
  const int t = blk & 511;
  const int th = t & 31, tw = t >> 5;
  const int h0 = th * 8, w0 = tw * 16;
  const int s0 = th * 32 + tw * 2;
  const int tid = threadIdx.x, lane = tid & 63, wid = tid >> 6;
  const int wr = wid >> 1, wc = wid & 1;
  const int g = lane >> 4, l15 = lane & 15;

  __shared__ u16 Ot[128 * 136];       // 34816 B — sole LDS

  bf16x8 bfrag[4][4];
  {
    const float* xb = x + (size_t)b * 8388608 + (size_t)(g * 8) * 65536
                        + (h0 + wc * 4) * 256 + w0 + l15;
    #pragma unroll
    for (int ks = 0; ks < 4; ++ks)
      #pragma unroll
      for (int e2 = 0; e2 < 4; ++e2) {
        const float* pa = xb + (size_t)(ks * 32 + e2 * 2) * 65536;
        const float* pb = pa + 65536;
        #pragma unroll
        for (int n = 0; n < 4; ++n)
          ((unsigned*)&bfrag[ks][n])[e2] = cvt_pk(pa[n * 256], pb[n * 256]);
      }
  }

  for (int sel = 0; sel < 3; ++sel) {
    const u16* w = WQKV + sel * 16384;
    const float* bias = sel == 0 ? bq : (sel == 1 ? bk : bv);
    u16* qkv = sel == 0 ? Q : (sel == 1 ? K : V);

    f32x4 acc[4][4] = {};
    #pragma unroll
    for (int ks = 0; ks < 4; ++ks) {
      bf16x8 a[4];
      #pragma unroll
      for (int m = 0; m < 4; ++m) {
        int o = wr * 64 + m * 16 + l15;
        a[m] = *(const bf16x8*)(w + o * 128 + ks * 32 + g * 8);
      }
      #pragma unroll
      for (int m = 0; m < 4; ++m)
        #pragma unroll
        for (int n = 0; n < 4; ++n)
          acc[m][n] = __builtin_amdgcn_mfma_f32_16x16x32_bf16(a[m], bfrag[ks][n], acc[m][n], 0, 0, 0);
    }

    float4 bias4[4];
    #pragma unroll
    for (int m = 0; m < 4; ++m)
      bias4[m] = *(const float4*)&bias[wr * 64 + m * 16 + g * 4];

    __syncthreads();
    #pragma unroll
    for (int m = 0; m < 4; ++m) {
      int o0 = wr * 64 + m * 16 + g * 4;
      #pragma unroll
      for (int n = 0; n < 4; ++n) {
        int p = wc * 64 + n * 16 + l15;
        unsigned r0 = cvt_pk(acc[m][n][0] + bias4[m].x, acc[m][n][1] + bias4[m].y);
        unsigned r1 = cvt_pk(acc[m][n][2] + bias4[m].z, acc[m][n][3] + bias4[m].w);
        unsigned* dp = (unsigned*)&Ot[p * 136 + o0];
        dp[0] = r0; dp[1] = r1;
      }
    }
    __syncthreads();
    #pragma unroll
    for (int it = 0; it < 8; ++it) {
      int head = it >> 1, s2 = it & 1;
      int pixw = tid >> 2;
      int dphc = tid & 3;
      int pl = (pixw >> 3) * 16 + s2 * 8 + (pixw & 7);
      bf16x8 vv = *(const bf16x8*)&Ot[pl * 136 + head * 32 + dphc * 8];
      size_t gaddr = ((size_t)((b * 4 + head) * 1024 + s0 + s2)) * 2048 + pixw * 32 + dphc * 8;
      *(bf16x8*)(qkv + gaddr) = vv;
    }
  }
}

// ---------------- K2: fused {EATT = exp(Q K^T * scale), row-sums} + {VT transpose} ----------------
// grid 1536: wgid<512 -> qk (bh = wgid&7, 3-buffer counted-vmcnt pipeline);
//            wgid>=512 -> vt (idx = wgid-512, bh = idx&7).
__global__ __launch_bounds__(256) void k_qkvt(const u16* __restrict__ Q,
                                              const u16* __restrict__ K,
                                              u16* __restrict__ EATT,
                                              const u16* __restrict__ V,
                                              u16* __restrict__ VT,
                                              float* __restrict__ RS) {
  __shared__ __align__(16) u16 smem[24576];   // 48 KB: 3 staging bufs; Ot/vt alias
  const int tid = threadIdx.x, lane = tid & 63, wid = tid >> 6;

  if (blockIdx.x < 512) {
    const int bh = blockIdx.x & 7;
    const int tile = blockIdx.x >> 3;
    const int tm = tile & 7, tn = tile >> 3;
    const int row0 = tm * 128, col0 = tn * 128;
    const int wr = wid >> 1, wc = wid & 1;
    const u16* Ab = Q + (size_t)bh * 1024 * 2048 + (size_t)row0 * 2048;
    const u16* Bb = K + (size_t)bh * 1024 * 2048 + (size_t)col0 * 2048;
    f32x4 acc[4][4] = {};
    const int lr = lane >> 2, lc = lane & 3;
    const int scs = lc ^ ((lr >> 1) & 3);
    const int rsw = ((lane & 15) >> 1) & 3;

    auto stage = [&](int k0, int bf) {       // 4 own vmem ops
      u16* As = smem + bf * 8192;
      u16* Bs = smem + 4096 + bf * 8192;
      const u16* s0 = Ab + (size_t)(wid * 16 + lr) * 2048 + k0 + scs * 8;
      gl2lds16(s0, &As[wid * 512]);
      gl2lds16(s0 + (size_t)64 * 2048, &As[2048 + wid * 512]);
      const u16* s1 = Bb + (size_t)(wid * 16 + lr) * 2048 + k0 + scs * 8;
      gl2lds16(s1, &Bs[wid * 512]);
      gl2lds16(s1 + (size_t)64 * 2048, &Bs[2048 + wid * 512]);
    };

    stage(0, 0);
    stage(32, 1);
    for (int it = 0; it < 64; ++it) {
      asm volatile("s_waitcnt vmcnt(4)" ::: "memory");   // own stage(it) landed
      __syncthreads();                                   // all waves landed; reads of it-1 done
      if (it + 2 < 64) stage((it + 2) * 32, (it + 2) % 3);
      const u16* As = smem + (it % 3) * 8192;
      const u16* Bs = smem + 4096 + (it % 3) * 8192;
      bf16x8 a[4], bb[4];
      const int g = lane >> 4;
      const int chp = (g ^ rsw) * 8;
      #pragma unroll
      for (int m = 0; m < 4; ++m)
        a[m] = *(const bf16x8*)&As[(wr * 64 + m * 16 + (lane & 15)) * 32 + chp];
      #pragma unroll
      for (int n = 0; n < 4; ++n)
        bb[n] = *(const bf16x8*)&Bs[(wc * 64 + n * 16 + (lane & 15)) * 32 + chp];
      #pragma unroll
      for (int m = 0; m < 4; ++m)
        #pragma unroll
        for (int n = 0; n < 4; ++n)
          acc[m][n] = __builtin_amdgcn_mfma_f32_16x16x32_bf16(a[m], bb[n], acc[m][n], 0, 0, 0);
    }
    const float scale = 0.02209708691207961f;  // 1/sqrt(2048)
    __syncthreads();                           // all reads done before Ot alias write
    u16* Ot = smem;
    float psum[4][4];
    #pragma unroll
    for (int m = 0; m < 4; ++m) {
      int r0 = wr * 64 + m * 16 + ((lane >> 4) << 2);
      #pragma unroll
      for (int j = 0; j < 4; ++j) psum[m][j] = 0.f;
      #pragma unroll
      for (int n = 0; n < 4; ++n) {
        int dv = wc * 64 + n * 16 + (lane & 15);
        #pragma unroll
        for (int j = 0; j < 4; ++j) {
          float e = __expf(acc[m][n][j] * scale);
          Ot[(r0 + j) * 136 + dv] = f2bf(e);
          psum[m][j] += e;
        }
      }
    }
    #pragma unroll
    for (int m = 0; m < 4; ++m)
      #pragma unroll
      for (int j = 0; j < 4; ++j) {
        float v = psum[m][j];
        v += __shfl_xor(v, 1, 64);
        v += __shfl_xor(v, 2, 64);
        v += __shfl_xor(v, 4, 64);
        v += __shfl_xor(v, 8, 64);
        if ((lane & 15) == 0) {
          int r = row0 + wr * 64 + m * 16 + ((lane >> 4) << 2) + j;
          atomicAdd(&RS[bh * 1024 + r], v);
        }
      }
    __syncthreads();
    u16* outb = EATT + (size_t)bh * 1024 * 1024 + (size_t)row0 * 1024 + col0;
    #pragma unroll
    for (int it = 0; it < 8; ++it) {
      int ci = it * 256 + tid;          // 0..2047
      int sl = ci >> 4;                 // q-row local
      int ch = ci & 15;                 // 8-col chunk
      bf16x8 vv = *(const bf16x8*)&Ot[sl * 136 + ch * 8];
      *(bf16x8*)(outb + (size_t)sl * 1024 + ch * 8) = vv;
    }
  } else {
    const int idx = blockIdx.x - 512;
    const int bh = idx & 7;
    const int t2 = idx >> 3;
    const int ts = t2 & 7, td = t2 >> 3;
    const int s0 = ts * 128, d0 = td * 128;
    u16* T = smem;                 // [dv][s], s-chunk XOR-swizzled
    const u16* Vb = V + (size_t)bh * 1024 * 2048 + (size_t)s0 * 2048 + d0;

    #pragma unroll
    for (int pass = 0; pass < 8; ++pass) {
      int r = pass * 16 + (tid >> 4);
      int c8 = (tid & 15) * 8;
      union { uint4 u; u16 e[8]; } d;
      d.u = *(const uint4*)(Vb + (size_t)r * 2048 + c8);
      int chunk = (r >> 3) ^ ((c8 >> 3) & 15);
      #pragma unroll
      for (int e = 0; e < 8; ++e)
        T[(c8 + e) * 128 + chunk * 8 + (r & 7)] = d.e[e];
    }
    __syncthreads();
    u16* VTb = VT + (size_t)bh * 2048 * 1024 + (size_t)d0 * 1024 + s0;
    #pragma unroll
    for (int pass = 0; pass < 8; ++pass) {
      int rd = pass * 16 + (tid >> 4);
      int c8 = (tid & 15) * 8;
      int chunk = (c8 >> 3) ^ ((rd >> 3) & 15);
      bf16x8 v = *(const bf16x8*)&T[rd * 128 + chunk * 8];
      *(bf16x8*)(VTb + (size_t)rd * 1024 + c8) = v;
    }
  }
}

// ---------------- K4: Y = (EATT V) / RS via VT, write NHWC ----------------
// grid 1024 1-D: bh = wgid&7; tm fastest. 3-buffer counted-vmcnt pipeline.
__global__ __launch_bounds__(256) void k_pv(const u16* __restrict__ EATT,
                                            const u16* __restrict__ VT,
                                            const float* __restrict__ RS,
                                            u16* __restrict__ Yn) {
  const int bh = blockIdx.x & 7;
  const int tile = blockIdx.x >> 3;
  const int tm = tile & 7, tn = tile >> 3;
  const int row0 = tm * 128, col0 = tn * 128;
  const int tid = threadIdx.x, lane = tid & 63, wid = tid >> 6;
  const int wr = wid >> 1, wc = wid & 1;
  __shared__ __align__(16) u16 smem[24576];   // 48 KB: 3 bufs; Ot alias
  u16* Ot = smem;
  const u16* Pb = EATT + (size_t)bh * 1024 * 1024 + (size_t)row0 * 1024;
  const u16* VTb = VT + (size_t)bh * 2048 * 1024 + (size_t)col0 * 1024;
  f32x4 acc[4][4] = {};
  const int lr = lane >> 2, lc = lane & 3;
  const int scs = lc ^ ((lr >> 1) & 3);
  const int rsw = ((lane & 15) >> 1) & 3;

  auto stage = [&](int k0, int bf) {
    u16* As = smem + bf * 8192;
    u16* Bs = smem + 4096 + bf * 8192;
    const u16* s0 = Pb + (size_t)(wid * 16 + lr) * 1024 + k0 + scs * 8;
    gl2lds16(s0, &As[wid * 512]);
    gl2lds16(s0 + (size_t)64 * 1024, &As[2048 + wid * 512]);
    const u16* s1 = VTb + (size_t)(wid * 16 + lr) * 1024 + k0 + scs * 8;
    gl2lds16(s1, &Bs[wid * 512]);
    gl2lds16(s1 + (size_t)64 * 1024, &Bs[2048 + wid * 512]);
  };

  stage(0, 0);
  stage(32, 1);
  for (int it = 0; it < 32; ++it) {
    asm volatile("s_waitcnt vmcnt(4)" ::: "memory");
    __syncthreads();
    if (it + 2 < 32) stage((it + 2) * 32, (it + 2) % 3);
    const u16* As = smem + (it % 3) * 8192;
    const u16* Bs = smem + 4096 + (it % 3) * 8192;
    bf16x8 a[4], bb[4];
    const int g = lane >> 4;
    const int chp = (g ^ rsw) * 8;
    #pragma unroll
    for (int m = 0; m < 4; ++m)
      a[m] = *(const bf16x8*)&As[(wr * 64 + m * 16 + (lane & 15)) * 32 + chp];
    #pragma unroll
    for (int n = 0; n < 4; ++n)
      bb[n] = *(const bf16x8*)&Bs[(wc * 64 + n * 16 + (lane & 15)) * 32 + chp];
    #pragma unroll
    for (int m = 0; m < 4; ++m)
      #pragma unroll
      for (int n = 0; n < 4; ++n)
        acc[m][n] = __builtin_amdgcn_mfma_f32_16x16x32_bf16(a[m], bb[n], acc[m][n], 0, 0, 0);
  }

  __syncthreads();                        // all reads done before Ot alias write
  #pragma unroll
  for (int m = 0; m < 4; ++m) {
    int r0 = wr * 64 + m * 16 + ((lane >> 4) << 2);
    float inv[4];
    #pragma unroll
    for (int j = 0; j < 4; ++j)
      inv[j] = 1.0f / RS[bh * 1024 + row0 + r0 + j];
    #pragma unroll
    for (int n = 0; n < 4; ++n) {
      int dv = wc * 64 + n * 16 + (lane & 15);
      #pragma unroll
      for (int j = 0; j < 4; ++j)
        Ot[(r0 + j) * 136 + dv] = f2bf(acc[m][n][j] * inv[j]);
    }
  }
  __syncthreads();
  const int b = bh >> 2, head = bh & 3;
  const int pixw0 = tn * 4;
  #pragma unroll
  for (int it = 0; it < 8; ++it) {
    int ci = it * 256 + tid;
    int sl = ci >> 4;
    int pxl = (ci >> 2) & 3;
    int dc = ci & 3;
    bf16x8 vv = *(const bf16x8*)&Ot[sl * 136 + pxl * 32 + dc * 8];
    int s = row0 + sl, oh = s >> 5, ow = s & 31;
    int pixw = pixw0 + pxl, ph = pixw >> 3, pw = pixw & 7;
    int h = oh * 8 + ph, w2 = ow * 8 + pw;
    size_t gaddr = (((size_t)(b * 256 + h) * 256) + w2) * 128 + head * 32 + dc * 8;
    *(bf16x8*)(Yn + gaddr) = vv;
  }
}

// ---------------- K5: 3x3 reflect conv + bias + LeakyReLU (NHWC in, NCHW fp32 out) ----------------
__global__ __launch_bounds__(512, 2) void k_conv(const u16* __restrict__ Yn,
                                                 const u16* __restrict__ WT,
                                                 const float* __restrict__ bo,
                                                 float* __restrict__ out) {
  const int wgid = blockIdx.x;
  const int r7 = wgid & 7;
  const int b = (r7 >> 2) & 1;
  const int w0 = ((r7 >> 1) & 1) * 128;
  const int h0 = ((r7 & 1) * 32 + (wgid >> 3)) * 4;     // 0,4,...,252
  const int tid = threadIdx.x, lane = tid & 63, wid = tid >> 6;
  const int wo_ = wid & 1;
  const int wh = wid >> 1;
  const int g = lane >> 4, l15 = lane & 15;
  __shared__ u16 S[6][136 * 64];
  __shared__ u16 WTl[2][8192];
  f32x4 acc[4][8] = {};

  auto stageS = [&](int chalf) {
    for (int g5 = wid; g5 < 102; g5 += 8) {
      int rowi = g5 / 17, grp = g5 % 17;
      int rg = grp * 8 + (lane >> 3);
      int chunk = lane & 7;
      int row = h0 + rowi - 1;
      row = row < 0 ? 1 : (row > 255 ? 254 : row);
      int wsrc = w0 - 1 + rg;
      wsrc = wsrc < 0 ? 1 : (wsrc > 255 ? 254 : wsrc);
      const u16* src = Yn + ((size_t)(b * 256 + row) * 256 + wsrc) * 128 + chalf * 64
                         + ((chunk ^ (rg & 7)) * 8);
      gl2lds16(src, &S[rowi][grp * 512]);
    }
  };
  auto stageWT = [&](int chalf, int tap, int nb) {
    #pragma unroll
    for (int r2 = 0; r2 < 2; ++r2) {
      int g5 = wid + r2 * 8;
      int orow = g5 * 8 + (lane >> 3);
      int csrc = (lane & 7) ^ (lane >> 3);
      const u16* src = WT + ((size_t)tap * 128 + orow) * 128 + chalf * 64 + csrc * 8;
      gl2lds16(src, &WTl[nb][g5 * 512]);
    }
  };

  int buf = 0;
  stageS(0);
  stageWT(0, 0, 0);
  asm volatile("s_waitcnt vmcnt(0)" ::: "memory");
  __syncthreads();

  #pragma unroll
  for (int chalf = 0; chalf < 2; ++chalf) {
    if (chalf) {
      __syncthreads();
      stageS(1);
      stageWT(1, 0, buf ^ 1);
      asm volatile("s_waitcnt vmcnt(0)" ::: "memory");
      __syncthreads();
      buf ^= 1;
    }
    #pragma unroll
    for (int ky = 0; ky < 3; ++ky) {
      #pragma unroll
      for (int kx = 0; kx < 3; ++kx) {
        const int tap = ky * 3 + kx;
        const bool hasNext = (tap < 8);
        if (hasNext) stageWT(chalf, tap + 1, buf ^ 1);
        bf16x8 areg[2][4];
        #pragma unroll
        for (int ckh = 0; ckh < 2; ++ckh)
          #pragma unroll
          for (int m = 0; m < 4; ++m) {
            int o = wo_ * 64 + m * 16 + l15;
            int cc2 = ((ckh << 2) + g) ^ (o & 7);
            areg[ckh][m] = *(const bf16x8*)&WTl[buf][o * 64 + cc2 * 8];
          }
        #pragma unroll
        for (int ckh = 0; ckh < 2; ++ckh) {
          #pragma unroll
          for (int nh = 0; nh < 2; ++nh) {
            bf16x8 bb[4];
            #pragma unroll
            for (int n4 = 0; n4 < 4; ++n4) {
              int p = (nh * 4 + n4) * 16 + l15 + kx;
              int chunk = ((ckh << 2) + g) ^ (p & 7);
              bb[n4] = *(const bf16x8*)&S[wh + ky][p * 64 + chunk * 8];
            }
            #pragma unroll
            for (int m = 0; m < 4; ++m)
              #pragma unroll
              for (int n4 = 0; n4 < 4; ++n4)
                acc[m][nh * 4 + n4] = __builtin_amdgcn_mfma_f32_16x16x32_bf16(
                    areg[ckh][m], bb[n4], acc[m][nh * 4 + n4], 0, 0, 0);
          }
        }
        if (hasNext) {
          asm volatile("s_waitcnt vmcnt(0)" ::: "memory");
          __syncthreads();
          buf ^= 1;
        }
      }
    }
  }
  #pragma unroll
  for (int m = 0; m < 4; ++m) {
    int o0 = wo_ * 64 + m * 16 + (g << 2);
    #pragma unroll
    for (int n = 0; n < 8; ++n) {
      int p = n * 16 + l15;
      #pragma unroll
      for (int j = 0; j < 4; ++j) {
        int o = o0 + j;
        float v = acc[m][n][j] + bo[o];
        v = v > 0.f ? v : 0.2f * v;
        out[(((size_t)b * 128 + o) << 16) + ((h0 + wh) << 8) + w0 + p] = v;
      }
    }
  }
}

extern "C" void kernel_launch(void* const* d_in, const int* in_sizes, int n_in,
                              void* d_out, int out_size, void* d_ws, size_t ws_size,
                              hipStream_t stream) {
  const float* x  = (const float*)d_in[0];
  // d_in[1] = mask: dead code in reference
  const float* wq = (const float*)d_in[2];
  const float* bq = (const float*)d_in[3];
  const float* wk = (const float*)d_in[4];
  const float* bk = (const float*)d_in[5];
  const float* wv = (const float*)d_in[6];
  const float* bv = (const float*)d_in[7];
  const float* wo = (const float*)d_in[8];
  const float* bo = (const float*)d_in[9];

  char* ws = (char*)d_ws;
  u16*   WT   = (u16*)(ws);                                 // 288 KiB
  u16*   WQKV = (u16*)(ws + (size_t)(512 << 10));           // 96 KiB
  u16*   Q   = (u16*)(ws + (size_t)(1  << 20));             // 32 MiB
  u16*   K   = (u16*)(ws + (size_t)(33 << 20));             // 32 MiB
  u16*   V   = (u16*)(ws + (size_t)(65 << 20));             // 32 MiB
  u16*   EATT= (u16*)(ws + (size_t)(97 << 20));             // 16 MiB bf16 exp
  float* RS  = (float*)(ws + (size_t)(129 << 20));          // 32 KiB row sums
  u16*   Yn  = (u16*)(ws + (size_t)(145 << 20));            // 32 MiB NHWC
  u16*   VT  = (u16*)(ws + (size_t)(177 << 20));            // 32 MiB [bh][d][s]
  float* outp = (float*)d_out;

  k_prep<<<800, 256, 0, stream>>>(wo, wq, wk, wv, WT, WQKV, RS);
  k_qkv<<<1024, 256, 0, stream>>>(x, WQKV, bq, bk, bv, Q, K, V);
  k_qkvt<<<1536, 256, 0, stream>>>(Q, K, EATT, V, VT, RS);
  k_pv<<<1024, 256, 0, stream>>>(EATT, VT, RS, Yn);
  k_conv<<<256, 512, 0, stream>>>(Yn, WT, bo, outp);
}